// Round 5
// baseline (17342.949 us; speedup 1.0000x reference)
//
#include <hip/hip_runtime.h>
#include <hip/hip_cooperative_groups.h>
#include <math.h>

#define RI __restrict__

namespace cg = cooperative_groups;

namespace {

constexpr int Hn=512, En=512, Vn=10000, Fn=1280, Pn=196, Bn=32, Tn=80;
constexpr int G4 = 2048, KX = 1792;
constexpr int NCAT = 13888;          // 512 hid + 1280 gate + 2048 xp + 10048 logits(pad)
constexpr int NVT = 157;
constexpr int J_GATE = 512, J_XP = 1792, J_LOG = 3840;
constexpr int NBLK = 256;

// ---- workspace layout (float indices) ----
constexpr long O_ENC  = 0;                           // [B*P][H]
constexpr long O_W2T  = O_ENC  + (long)Bn*Pn*Hn;     // [F][H]
constexpr long O_WCAT = O_W2T  + (long)Fn*Hn;        // [512][NCAT] (w1T|gwT|whhT|owT)
constexpr long O_WIHT = O_WCAT + (long)Hn*NCAT;      // [KX][2048] permuted cols (pc=i*4+g)
constexpr long O_H    = O_WIHT + (long)KX*G4;        // [B][H]
constexpr long O_HT   = O_H    + (long)Bn*Hn;        // [H][B]
constexpr long O_C    = O_HT   + (long)Hn*Bn;        // [B][H]
constexpr long O_HID  = O_C    + (long)Bn*Hn;        // [B][H]
constexpr long O_GT   = O_HID  + (long)Bn*Hn;        // [F][B]
constexpr long O_XPT  = O_GT   + (long)Fn*Bn;        // [2048 pc][B]
constexpr long O_XT   = O_XPT  + (long)G4*Bn;        // [KX][B]
constexpr long O_PMV  = O_XT   + (long)KX*Bn;        // [B][157]
constexpr long O_PMI  = O_PMV  + (long)Bn*NVT;       // [B][157] int
// setup-only aliases inside O_ENC (consumed before k_encproj overwrites)
constexpr long O_IHCT  = O_ENC;                      // [1280][1024] (ihwT|icwT)
constexpr long O_MEANT = O_ENC + (long)Fn*1024;      // [F][B]

__device__ __forceinline__ float sigm(float x){ return 1.0f/(1.0f+expf(-x)); }
__device__ __forceinline__ void fma4(float4& a, const float4 x, const float w){
  a.x += w*x.x; a.y += w*x.y; a.z += w*x.z; a.w += w*x.w;
}

// ---------- transpose with dst stride: dst[c*S + r] = src[r*C + c] ----------
__global__ __launch_bounds__(256) void k_tr_s(const float* RI src, float* RI dst,
                                              int R, int C, int S){
  __shared__ float t[32][33];
  int tc0 = blockIdx.x*32, tr0 = blockIdx.y*32;
  int lx = threadIdx.x & 31, ly = threadIdx.x >> 5;
  for (int i = ly; i < 32; i += 8){
    int r = tr0 + i, c = tc0 + lx;
    t[i][lx] = (r < R && c < C) ? src[(long)r*C + c] : 0.f;
  }
  __syncthreads();
  for (int i = ly; i < 32; i += 8){
    int c = tc0 + i, r = tr0 + lx;
    if (c < C && r < R) dst[(long)c*S + r] = t[lx][i];
  }
}

// ---------- wih transpose, gate-interleaved cols: WIHT[k][pc]=wih[j][k], pc=(j&511)*4+(j>>9)
__global__ __launch_bounds__(256) void k_tr_wih(const float* RI src, float* RI ws){
  __shared__ float t[32][33];
  int tk0 = blockIdx.x*32, tj0 = blockIdx.y*32;
  int lx = threadIdx.x & 31, ly = threadIdx.x >> 5;
  for (int i = ly; i < 32; i += 8){
    int j = tj0 + i, k = tk0 + lx;
    t[i][lx] = src[(long)j*KX + k];
  }
  __syncthreads();
  for (int i = ly; i < 32; i += 8){
    int k = tk0 + i, j = tj0 + lx;
    int pc = ((j & 511) << 2) | (j >> 9);
    ws[O_WIHT + (long)k*G4 + pc] = t[lx][i];
  }
}

// ---------- meanT[f][b] ----------
__global__ __launch_bounds__(256) void k_mean(const float* RI feat, float* RI ws){
  int blk = blockIdx.x;             // 160 = 32 b x 5 f-tiles
  int b = blk / 5, ft = blk % 5;
  int f = ft*256 + threadIdx.x;
  float s = 0.f;
  const float* fp = feat + (long)b*Pn*Fn + f;
  for (int p = 0; p < Pn; ++p) s += fp[(long)p*Fn];
  ws[O_MEANT + (long)f*Bn + b] = s * (1.0f/Pn);
}

// ---------- h0,c0 ----------
__global__ __launch_bounds__(512) void k_h0c0(const float* RI ihb, const float* RI icb,
                                              float* RI ws){
  int tid = threadIdx.x;
  int jl = tid & 63, bq = tid >> 6;
  int j = blockIdx.x*64 + jl;
  const float* wp = ws + O_IHCT + j;
  const float* xp = ws + O_MEANT + bq*4;
  float4 acc = make_float4(0,0,0,0);
  for (int k = 0; k < Fn; ++k){
    float w = wp[(long)k*1024];
    float4 x = *(const float4*)(xp + (long)k*Bn);
    fma4(acc, x, w);
  }
  float va[4] = {acc.x, acc.y, acc.z, acc.w};
  if (j < Hn){
    float bias = ihb[j];
    #pragma unroll
    for (int m = 0; m < 4; ++m){
      int b = bq*4 + m;
      float v = va[m] + bias;
      ws[O_H  + (long)b*Hn + j] = v;
      ws[O_HT + (long)j*Bn + b] = v;
    }
  } else {
    int j2 = j - Hn;
    float bias = icb[j2];
    #pragma unroll
    for (int m = 0; m < 4; ++m)
      ws[O_C + (long)(bq*4+m)*Hn + j2] = va[m] + bias;
  }
}

// ---------- enc_proj: 392 blocks = 98 rt x 4 ct; 64 rows x 128 j per block ----------
__global__ __launch_bounds__(512) void k_encproj(const float* RI feat, const float* RI w2b,
                                                 float* RI ws){
  __shared__ __align__(16) float xs[64*65];
  const int blk = blockIdx.x;
  const int rt = blk >> 2, ct = blk & 3;
  const int r0 = rt*64, j0 = ct*128;
  const int tid = threadIdx.x;
  const int jq = tid & 31, rg = tid >> 5;     // j = j0+jq*4 ; rows r0+rg*4..+4
  const int rw = tid >> 3, kc = (tid & 7)*8;  // staging: row rw, k-chunk kc..kc+8
  const float* w2t = ws + O_W2T + j0 + jq*4;
  float4 a0 = make_float4(0,0,0,0), a1 = a0, a2 = a0, a3 = a0;
  for (int k0 = 0; k0 < Fn; k0 += 64){
    __syncthreads();
    {
      const float* fp = feat + (long)(r0+rw)*Fn + k0 + kc;
      float4 v0 = *(const float4*)(fp);
      float4 v1 = *(const float4*)(fp + 4);
      float* xr = xs + rw*65 + kc;
      xr[0]=v0.x; xr[1]=v0.y; xr[2]=v0.z; xr[3]=v0.w;
      xr[4]=v1.x; xr[5]=v1.y; xr[6]=v1.z; xr[7]=v1.w;
    }
    __syncthreads();
    #pragma unroll 4
    for (int kk = 0; kk < 64; ++kk){
      float4 w = *(const float4*)(w2t + (long)(k0+kk)*Hn);
      const float* xp = xs + (rg*4)*65 + kk;
      fma4(a0, w, xp[0]);
      fma4(a1, w, xp[65]);
      fma4(a2, w, xp[130]);
      fma4(a3, w, xp[195]);
    }
  }
  float4 b4 = *(const float4*)(w2b + j0 + jq*4);
  float4 out[4] = {a0,a1,a2,a3};
  #pragma unroll
  for (int m = 0; m < 4; ++m){
    long r = r0 + rg*4 + m;
    float4 o = out[m];
    o.x += b4.x; o.y += b4.y; o.z += b4.z; o.w += b4.w;
    *(float4*)(ws + O_ENC + r*Hn + j0 + jq*4) = o;
  }
}

// ---------- the whole 80-step decode: ONE cooperative kernel ----------
// 256 blocks x 512 threads. 3 grid.sync() per step.
__global__ __launch_bounds__(512, 2) void k_decode(
    const float* RI feat, const float* RI emb, const float* RI vaw, const float* RI vab,
    const float* RI w1b, const float* RI gb, const float* RI bih, const float* RI bhh,
    const float* RI outb, float* RI ws, float* RI dout)
{
  __shared__ __align__(16) float smem[16384];   // 64 KB, re-aliased per phase
  cg::grid_group gg = cg::this_grid();
  const int blk = blockIdx.x, tid = threadIdx.x;

  for (int t = 0; t <= Tn; ++t){
    // ================= P1: unified h-GEMM (+logits_{t-1}, argmax partials) =================
    if (t == Tn && blk < 2){
      const float* src = ws + (blk == 0 ? O_H : O_C);
      float* dst = dout + (long)Bn*Tn*Vn + (long)blk*Bn*Hn;
      for (int i = tid; i < Bn*Hn; i += 512) dst[i] = src[i];
    }
    bool act = (t == Tn) ? (blk >= 60 && blk < 217)
                         : (blk < 217 && !(t == 0 && blk >= 60));
    if (act){
      float4* P4 = (float4*)smem;           // [8][512]
      const int jl = tid & 63, wv = tid >> 6;
      const int j = blk*64 + jl;
      const float* wp = ws + O_WCAT + j;
      float4 acc[8];
      #pragma unroll
      for (int q = 0; q < 8; ++q) acc[q] = make_float4(0,0,0,0);
      const int kb = wv*64;
      for (int k = kb; k < kb + 64; ++k){
        float w = wp[(long)k*NCAT];
        const float4* xr = (const float4*)(ws + O_HT + (long)k*Bn);
        #pragma unroll
        for (int q = 0; q < 8; ++q) fma4(acc[q], xr[q], w);
      }
      #pragma unroll
      for (int q = 0; q < 8; ++q) P4[q*512 + wv*64 + jl] = acc[q];
      __syncthreads();
      const int bq = wv;
      float4 s = make_float4(0,0,0,0);
      #pragma unroll
      for (int w = 0; w < 8; ++w){
        float4 p = P4[bq*512 + w*64 + jl];
        s.x += p.x; s.y += p.y; s.z += p.z; s.w += p.w;
      }
      if (blk < 8){                      // hid
        float bias = w1b[j];
        ws[O_HID + (long)(bq*4+0)*Hn + j] = s.x + bias;
        ws[O_HID + (long)(bq*4+1)*Hn + j] = s.y + bias;
        ws[O_HID + (long)(bq*4+2)*Hn + j] = s.z + bias;
        ws[O_HID + (long)(bq*4+3)*Hn + j] = s.w + bias;
      } else if (blk < 28){              // gate
        int f = j - J_GATE;
        float bias = gb[f];
        float4 g = make_float4(sigm(s.x+bias), sigm(s.y+bias),
                               sigm(s.z+bias), sigm(s.w+bias));
        *(float4*)(ws + O_GT + (long)f*Bn + bq*4) = g;
      } else if (blk < 60){              // xpart (permuted col layout)
        int j2 = j - J_XP;
        int pc = ((j2 & 511) << 2) | (j2 >> 9);
        float bias = bih[j2] + bhh[j2];
        float4 a = make_float4(s.x+bias, s.y+bias, s.z+bias, s.w+bias);
        *(float4*)(ws + O_XPT + (long)pc*Bn + bq*4) = a;
      } else {                           // logits_{t-1} + argmax partials
        int v = j - J_LOG;
        float lv[4];
        if (v < Vn){
          float bias = outb[v];
          lv[0]=s.x+bias; lv[1]=s.y+bias; lv[2]=s.z+bias; lv[3]=s.w+bias;
          #pragma unroll
          for (int m = 0; m < 4; ++m)
            dout[((long)(bq*4+m)*Tn + (t-1))*Vn + v] = lv[m];
        } else {
          lv[0]=lv[1]=lv[2]=lv[3]=-1e30f;
        }
        int tile = blk - 60;
        #pragma unroll
        for (int m = 0; m < 4; ++m){
          float bv = lv[m]; int bi = v;
          #pragma unroll
          for (int off = 32; off; off >>= 1){
            float ov = __shfl_down(bv, off, 64);
            int   oi = __shfl_down(bi, off, 64);
            if (ov > bv || (ov == bv && oi < bi)){ bv = ov; bi = oi; }
          }
          if (jl == 0){
            int b = bq*4 + m;
            ws[O_PMV + (long)b*NVT + tile] = bv;
            ((int*)(ws + O_PMI))[(long)b*NVT + tile] = bi;
          }
        }
      }
    }
    gg.sync();
    if (t == Tn) break;

    // ================= P2: attention + argmax finalize + xT build =================
    if (blk < 64){
      float* hid_s = smem;                // 512
      float* sval  = smem + 512;          // 256
      float* wts_s = smem + 768;          // 256
      float* invp  = smem + 1024;         // 1
      int*   selp  = (int*)(smem + 1032); // 1
      if (blk < 32){
        const int b = blk;
        hid_s[tid] = ws[O_HID + (long)b*Hn + tid];
        __syncthreads();
        {
          int w = tid >> 6, l = tid & 63;
          const float* eb = ws + O_ENC + (long)b*Pn*Hn;
          for (int p = w; p < Pn; p += 8){
            const float* er = eb + (long)p*Hn;
            float4 e0 = *(const float4*)(er + l*4);
            float4 e1 = *(const float4*)(er + 256 + l*4);
            float4 h0 = *(const float4*)(hid_s + l*4);
            float4 h1 = *(const float4*)(hid_s + 256 + l*4);
            float4 v0 = *(const float4*)(vaw + l*4);
            float4 v1 = *(const float4*)(vaw + 256 + l*4);
            float s = fmaxf(h0.x+e0.x,0.f)*v0.x + fmaxf(h0.y+e0.y,0.f)*v0.y
                    + fmaxf(h0.z+e0.z,0.f)*v0.z + fmaxf(h0.w+e0.w,0.f)*v0.w
                    + fmaxf(h1.x+e1.x,0.f)*v1.x + fmaxf(h1.y+e1.y,0.f)*v1.y
                    + fmaxf(h1.z+e1.z,0.f)*v1.z + fmaxf(h1.w+e1.w,0.f)*v1.w;
            #pragma unroll
            for (int off = 32; off; off >>= 1) s += __shfl_down(s, off, 64);
            if (l == 0) sval[p] = s + vab[0];
          }
        }
        __syncthreads();
        if (tid < 64){
          float m = -1e30f;
          for (int p = tid; p < Pn; p += 64) m = fmaxf(m, sval[p]);
          #pragma unroll
          for (int off = 32; off; off >>= 1) m = fmaxf(m, __shfl_xor(m, off, 64));
          float s = 0.f;
          for (int p = tid; p < Pn; p += 64){
            float e = expf(sval[p] - m);
            sval[p] = e; s += e;
          }
          #pragma unroll
          for (int off = 32; off; off >>= 1) s += __shfl_xor(s, off, 64);
          if (tid == 0) invp[0] = 1.0f/s;
        }
        __syncthreads();
        if (tid < Pn){
          float wv = sval[tid] * invp[0];
          wts_s[tid] = wv;
          dout[(long)Bn*Tn*Vn + 2L*Bn*Hn + ((long)b*Tn + t)*Pn + tid] = wv;
        }
        __syncthreads();
        {
          const float* fb = feat + (long)b*Pn*Fn;
          float a0 = 0.f, a1 = 0.f, a2 = 0.f;
          for (int p = 0; p < Pn; ++p){
            float wv = wts_s[p];
            const float* fp = fb + (long)p*Fn;
            a0 += wv * fp[tid];
            a1 += wv * fp[tid + 512];
            if (tid < 256) a2 += wv * fp[tid + 1024];
          }
          a0 *= ws[O_GT + (long)tid*Bn + b];
          a1 *= ws[O_GT + (long)(tid+512)*Bn + b];
          ws[O_XT + (long)(En + tid)*Bn + b] = a0;
          ws[O_XT + (long)(En + tid + 512)*Bn + b] = a1;
          if (tid < 256){
            a2 *= ws[O_GT + (long)(tid+1024)*Bn + b];
            ws[O_XT + (long)(En + tid + 1024)*Bn + b] = a2;
          }
        }
      } else {
        const int b = blk - 32;
        if (t == 0){
          if (tid == 0) selp[0] = 1;        // SOS
        } else if (tid < 64){
          float bv = -1e30f; int bi = 0x7fffffff;
          for (int q = tid; q < NVT; q += 64){
            float cv = ws[O_PMV + (long)b*NVT + q];
            if (cv > bv){ bv = cv; bi = ((const int*)(ws + O_PMI))[(long)b*NVT + q]; }
          }
          #pragma unroll
          for (int off = 32; off; off >>= 1){
            float ov = __shfl_down(bv, off, 64);
            int   oi = __shfl_down(bi, off, 64);
            if (ov > bv || (ov == bv && oi < bi)){ bv = ov; bi = oi; }
          }
          if (tid == 0) selp[0] = bi;
        }
        __syncthreads();
        int row = selp[0];
        ws[O_XT + (long)tid*Bn + b] = emb[(long)row*En + tid];
      }
    }
    gg.sync();

    // ================= P3: Wih GEMM (permuted cols) + LSTM update =================
    {
      float* red  = smem;            // [8*16][16] = 2048
      float* gbuf = smem + 2048;     // [16][16]
      const int ct = blk >> 1, bh = blk & 1;
      const int c0 = ct*16;
      const int sk = tid >> 6, lane = tid & 63;
      const int cl = lane & 15, bs = lane >> 4;
      const float* wp = ws + O_WIHT + c0 + cl;
      const float* xp = ws + O_XT + bh*16 + bs*4;
      float4 acc = make_float4(0,0,0,0);
      const int kb = sk*224;
      for (int k = kb; k < kb + 224; ++k){
        float w = wp[(long)k*G4];
        float4 x = *(const float4*)(xp + (long)k*Bn);
        fma4(acc, x, w);
      }
      *(float4*)(red + (sk*16 + cl)*16 + bs*4) = acc;
      __syncthreads();
      if (tid < 256){
        int c = tid >> 4, bl = tid & 15;
        float s = 0.f;
        #pragma unroll
        for (int q = 0; q < 8; ++q) s += red[(q*16 + c)*16 + bl];
        s += ws[O_XPT + (long)(c0 + c)*Bn + bh*16 + bl];
        gbuf[c*16 + bl] = s;
      }
      __syncthreads();
      if (tid < 64){
        int il = tid >> 4, bl = tid & 15;
        int i = ct*4 + il, b = bh*16 + bl;
        float gi = gbuf[(il*4+0)*16 + bl];
        float gf = gbuf[(il*4+1)*16 + bl];
        float gg2 = gbuf[(il*4+2)*16 + bl];
        float go = gbuf[(il*4+3)*16 + bl];
        float c_ = ws[O_C + (long)b*Hn + i];
        float cn = sigm(gf)*c_ + sigm(gi)*tanhf(gg2);
        float hn = sigm(go)*tanhf(cn);
        ws[O_C  + (long)b*Hn + i] = cn;
        ws[O_H  + (long)b*Hn + i] = hn;
        ws[O_HT + (long)i*Bn + b] = hn;
      }
    }
    gg.sync();
  }
}

} // anonymous namespace

extern "C" void kernel_launch(void* const* d_in, const int* in_sizes, int n_in,
                              void* d_out, int out_size, void* d_ws, size_t ws_size,
                              hipStream_t stream)
{
  (void)in_sizes; (void)n_in; (void)out_size; (void)ws_size;
  const float* feat = (const float*)d_in[0];
  const float* emb  = (const float*)d_in[3];
  const float* w1w  = (const float*)d_in[4];
  const float* w1b  = (const float*)d_in[5];
  const float* w2w  = (const float*)d_in[6];
  const float* w2b  = (const float*)d_in[7];
  const float* vaw  = (const float*)d_in[8];
  const float* vab  = (const float*)d_in[9];
  const float* wih  = (const float*)d_in[10];
  const float* whh  = (const float*)d_in[11];
  const float* bih  = (const float*)d_in[12];
  const float* bhh  = (const float*)d_in[13];
  const float* outw = (const float*)d_in[14];
  const float* outb = (const float*)d_in[15];
  const float* ihw  = (const float*)d_in[16];
  const float* ihb  = (const float*)d_in[17];
  const float* icw  = (const float*)d_in[18];
  const float* icb  = (const float*)d_in[19];
  const float* gw   = (const float*)d_in[20];
  const float* gb   = (const float*)d_in[21];
  float* ws  = (float*)d_ws;
  float* out = (float*)d_out;

  // setup: transposes of ihw/icw into ENC alias, mean, h0/c0
  k_tr_s<<<dim3(40,16),  256, 0, stream>>>(ihw,  ws + O_IHCT,       Hn, Fn, 1024);
  k_tr_s<<<dim3(40,16),  256, 0, stream>>>(icw,  ws + O_IHCT + 512, Hn, Fn, 1024);
  k_mean<<<160, 256, 0, stream>>>(feat, ws);
  k_h0c0<<<16, 512, 0, stream>>>(ihb, icb, ws);
  // persistent weight transposes
  k_tr_s<<<dim3(16,16),  256, 0, stream>>>(w1w,  ws + O_WCAT,          Hn, Hn, NCAT);
  k_tr_s<<<dim3(16,40),  256, 0, stream>>>(gw,   ws + O_WCAT + J_GATE, Fn, Hn, NCAT);
  k_tr_s<<<dim3(16,64),  256, 0, stream>>>(whh,  ws + O_WCAT + J_XP,   G4, Hn, NCAT);
  k_tr_s<<<dim3(16,313), 256, 0, stream>>>(outw, ws + O_WCAT + J_LOG,  Vn, Hn, NCAT);
  k_tr_wih<<<dim3(56,64), 256, 0, stream>>>(wih, ws);
  k_tr_s<<<dim3(40,16),  256, 0, stream>>>(w2w,  ws + O_W2T,           Hn, Fn, Hn);
  k_encproj<<<392, 512, 0, stream>>>(feat, w2b, ws);

  // the whole decode loop: one cooperative launch
  void* kargs[] = { (void*)&feat, (void*)&emb, (void*)&vaw, (void*)&vab,
                    (void*)&w1b, (void*)&gb, (void*)&bih, (void*)&bhh,
                    (void*)&outb, (void*)&ws, (void*)&out };
  hipLaunchCooperativeKernel((const void*)k_decode, dim3(NBLK), dim3(512),
                             kargs, 0, stream);
}

// Round 6
// 14980.946 us; speedup vs baseline: 1.1577x; 1.1577x over previous
//
#include <hip/hip_runtime.h>
#include <hip/hip_cooperative_groups.h>
#include <math.h>

#define RI __restrict__

namespace cg = cooperative_groups;

namespace {

constexpr int Hn=512, En=512, Vn=10000, Fn=1280, Pn=196, Bn=32, Tn=80;
constexpr int G4 = 2048, KX = 1792;
constexpr int NCAT = 13888;          // 512 hid + 1280 gate + 2048 xp + 10048 logits(pad)
constexpr int NVT = 157;
constexpr int J_GATE = 512, J_XP = 1792, J_LOG = 3840;
constexpr int NBLK = 256;

// ---- workspace layout (float indices) ----
constexpr long O_ENC  = 0;                           // [B*P][H]
constexpr long O_W2T  = O_ENC  + (long)Bn*Pn*Hn;     // [F][H]
constexpr long O_WCAT = O_W2T  + (long)Fn*Hn;        // [512][NCAT] (w1T|gwT|whhT|owT)
constexpr long O_WIHT = O_WCAT + (long)Hn*NCAT;      // [KX][2048] permuted cols (pc=i*4+g)
constexpr long O_H    = O_WIHT + (long)KX*G4;        // [B][H]
constexpr long O_HT   = O_H    + (long)Bn*Hn;        // [H][B]
constexpr long O_C    = O_HT   + (long)Hn*Bn;        // [B][H]
constexpr long O_HID  = O_C    + (long)Bn*Hn;        // [B][H]
constexpr long O_GT   = O_HID  + (long)Bn*Hn;        // [F][B]
constexpr long O_XPT  = O_GT   + (long)Fn*Bn;        // [2048 pc][B]
constexpr long O_XT   = O_XPT  + (long)G4*Bn;        // [KX][B]
constexpr long O_PMV  = O_XT   + (long)KX*Bn;        // [B][157]
constexpr long O_PMI  = O_PMV  + (long)Bn*NVT;       // [B][157] int
constexpr long O_SVAL = O_PMI  + (long)Bn*NVT;       // [B][196] raw scores
constexpr long O_SEL  = O_SVAL + (long)Bn*Pn;        // [B] int
// setup-only aliases inside O_ENC (consumed before k_encproj overwrites)
constexpr long O_IHCT  = O_ENC;                      // [1280][1024] (ihwT|icwT)
constexpr long O_MEANT = O_ENC + (long)Fn*1024;      // [F][B]

__device__ __forceinline__ float sigm(float x){ return 1.0f/(1.0f+expf(-x)); }
__device__ __forceinline__ void fma4(float4& a, const float4 x, const float w){
  a.x += w*x.x; a.y += w*x.y; a.z += w*x.z; a.w += w*x.w;
}

// ---------- transpose with dst stride: dst[c*S + r] = src[r*C + c] ----------
__global__ __launch_bounds__(256) void k_tr_s(const float* RI src, float* RI dst,
                                              int R, int C, int S){
  __shared__ float t[32][33];
  int tc0 = blockIdx.x*32, tr0 = blockIdx.y*32;
  int lx = threadIdx.x & 31, ly = threadIdx.x >> 5;
  for (int i = ly; i < 32; i += 8){
    int r = tr0 + i, c = tc0 + lx;
    t[i][lx] = (r < R && c < C) ? src[(long)r*C + c] : 0.f;
  }
  __syncthreads();
  for (int i = ly; i < 32; i += 8){
    int c = tc0 + i, r = tr0 + lx;
    if (c < C && r < R) dst[(long)c*S + r] = t[lx][i];
  }
}

// ---------- wih transpose, gate-interleaved cols: WIHT[k][pc]=wih[j][k], pc=(j&511)*4+(j>>9)
__global__ __launch_bounds__(256) void k_tr_wih(const float* RI src, float* RI ws){
  __shared__ float t[32][33];
  int tk0 = blockIdx.x*32, tj0 = blockIdx.y*32;
  int lx = threadIdx.x & 31, ly = threadIdx.x >> 5;
  for (int i = ly; i < 32; i += 8){
    int j = tj0 + i, k = tk0 + lx;
    t[i][lx] = src[(long)j*KX + k];
  }
  __syncthreads();
  for (int i = ly; i < 32; i += 8){
    int k = tk0 + i, j = tj0 + lx;
    int pc = ((j & 511) << 2) | (j >> 9);
    ws[O_WIHT + (long)k*G4 + pc] = t[lx][i];
  }
}

// ---------- meanT[f][b] ----------
__global__ __launch_bounds__(256) void k_mean(const float* RI feat, float* RI ws){
  int blk = blockIdx.x;             // 160 = 32 b x 5 f-tiles
  int b = blk / 5, ft = blk % 5;
  int f = ft*256 + threadIdx.x;
  float s = 0.f;
  const float* fp = feat + (long)b*Pn*Fn + f;
  for (int p = 0; p < Pn; ++p) s += fp[(long)p*Fn];
  ws[O_MEANT + (long)f*Bn + b] = s * (1.0f/Pn);
}

// ---------- h0,c0 ----------
__global__ __launch_bounds__(512) void k_h0c0(const float* RI ihb, const float* RI icb,
                                              float* RI ws){
  int tid = threadIdx.x;
  int jl = tid & 63, bq = tid >> 6;
  int j = blockIdx.x*64 + jl;
  const float* wp = ws + O_IHCT + j;
  const float* xp = ws + O_MEANT + bq*4;
  float4 acc = make_float4(0,0,0,0);
  for (int k = 0; k < Fn; ++k){
    float w = wp[(long)k*1024];
    float4 x = *(const float4*)(xp + (long)k*Bn);
    fma4(acc, x, w);
  }
  float va[4] = {acc.x, acc.y, acc.z, acc.w};
  if (j < Hn){
    float bias = ihb[j];
    #pragma unroll
    for (int m = 0; m < 4; ++m){
      int b = bq*4 + m;
      float v = va[m] + bias;
      ws[O_H  + (long)b*Hn + j] = v;
      ws[O_HT + (long)j*Bn + b] = v;
    }
  } else {
    int j2 = j - Hn;
    float bias = icb[j2];
    #pragma unroll
    for (int m = 0; m < 4; ++m)
      ws[O_C + (long)(bq*4+m)*Hn + j2] = va[m] + bias;
  }
}

// ---------- enc_proj: 392 blocks = 98 rt x 4 ct; 64 rows x 128 j per block ----------
__global__ __launch_bounds__(512) void k_encproj(const float* RI feat, const float* RI w2b,
                                                 float* RI ws){
  __shared__ __align__(16) float xs[64*65];
  const int blk = blockIdx.x;
  const int rt = blk >> 2, ct = blk & 3;
  const int r0 = rt*64, j0 = ct*128;
  const int tid = threadIdx.x;
  const int jq = tid & 31, rg = tid >> 5;
  const int rw = tid >> 3, kc = (tid & 7)*8;
  const float* w2t = ws + O_W2T + j0 + jq*4;
  float4 a0 = make_float4(0,0,0,0), a1 = a0, a2 = a0, a3 = a0;
  for (int k0 = 0; k0 < Fn; k0 += 64){
    __syncthreads();
    {
      const float* fp = feat + (long)(r0+rw)*Fn + k0 + kc;
      float4 v0 = *(const float4*)(fp);
      float4 v1 = *(const float4*)(fp + 4);
      float* xr = xs + rw*65 + kc;
      xr[0]=v0.x; xr[1]=v0.y; xr[2]=v0.z; xr[3]=v0.w;
      xr[4]=v1.x; xr[5]=v1.y; xr[6]=v1.z; xr[7]=v1.w;
    }
    __syncthreads();
    #pragma unroll 4
    for (int kk = 0; kk < 64; ++kk){
      float4 w = *(const float4*)(w2t + (long)(k0+kk)*Hn);
      const float* xp = xs + (rg*4)*65 + kk;
      fma4(a0, w, xp[0]);
      fma4(a1, w, xp[65]);
      fma4(a2, w, xp[130]);
      fma4(a3, w, xp[195]);
    }
  }
  float4 b4 = *(const float4*)(w2b + j0 + jq*4);
  float4 out[4] = {a0,a1,a2,a3};
  #pragma unroll
  for (int m = 0; m < 4; ++m){
    long r = r0 + rg*4 + m;
    float4 o = out[m];
    o.x += b4.x; o.y += b4.y; o.z += b4.z; o.w += b4.w;
    *(float4*)(ws + O_ENC + r*Hn + j0 + jq*4) = o;
  }
}

// ---------- the whole 80-step decode: ONE cooperative kernel ----------
// 256 blocks x 512 threads, 1 block/CU, WCAT slice pinned in LDS (128 KB).
__global__ __launch_bounds__(512, 2) void k_decode(
    const float* RI feat, const float* RI emb, const float* RI vaw, const float* RI vab,
    const float* RI w1b, const float* RI gb, const float* RI bih, const float* RI bhh,
    const float* RI outb, float* RI ws, float* RI dout)
{
  __shared__ __align__(16) float wlds[512*64];   // 128 KB pinned WCAT slice [k][64 j]
  __shared__ __align__(16) float scr[3072];      // 12 KB phase scratch
  cg::grid_group gg = cg::this_grid();
  const int blk = blockIdx.x, tid = threadIdx.x;
  const int jl = tid & 63, bq = tid >> 6;

  // ---- one-time: stage this block's WCAT slice into LDS ----
  if (blk < 217){
    const float* wg = ws + O_WCAT + blk*64;
    for (int idx = tid; idx < 512*64; idx += 512){
      int k = idx >> 6, j = idx & 63;
      wlds[idx] = wg[(long)k*NCAT + j];
    }
  }
  __syncthreads();

  for (int t = 0; t <= Tn; ++t){
    // ================= P1: unified h-GEMM from LDS weights =================
    if (t == Tn && blk < 2){
      const float* src = ws + (blk == 0 ? O_H : O_C);
      float* dst = dout + (long)Bn*Tn*Vn + (long)blk*Bn*Hn;
      for (int i = tid; i < Bn*Hn; i += 512) dst[i] = src[i];
    }
    bool doP1 = (t == Tn) ? (blk >= 60 && blk < 217)
                          : (blk < 217 && !(t == 0 && blk >= 60));
    if (doP1){
      const float4* HT4 = (const float4*)(ws + O_HT);
      float4 acc = make_float4(0,0,0,0);
      #pragma unroll 8
      for (int k = 0; k < Hn; ++k){
        float w = wlds[(k << 6) + jl];
        float4 x = HT4[(k << 3) + bq];
        fma4(acc, x, w);
      }
      const int j = blk*64 + jl;
      if (blk < 8){                      // hid
        float bias = w1b[j];
        ws[O_HID + (long)(bq*4+0)*Hn + j] = acc.x + bias;
        ws[O_HID + (long)(bq*4+1)*Hn + j] = acc.y + bias;
        ws[O_HID + (long)(bq*4+2)*Hn + j] = acc.z + bias;
        ws[O_HID + (long)(bq*4+3)*Hn + j] = acc.w + bias;
      } else if (blk < 28){              // gate (sigmoid)
        int f = j - J_GATE;
        float bias = gb[f];
        float4 g = make_float4(sigm(acc.x+bias), sigm(acc.y+bias),
                               sigm(acc.z+bias), sigm(acc.w+bias));
        *(float4*)(ws + O_GT + (long)f*Bn + bq*4) = g;
      } else if (blk < 60){              // xpart (permuted col layout)
        int j2 = j - J_XP;
        int pc = ((j2 & 511) << 2) | (j2 >> 9);
        float bias = bih[j2] + bhh[j2];
        float4 a = make_float4(acc.x+bias, acc.y+bias, acc.z+bias, acc.w+bias);
        *(float4*)(ws + O_XPT + (long)pc*Bn + bq*4) = a;
      } else {                           // logits_{t-1} + argmax partials
        int v = j - J_LOG;
        float lv[4];
        if (v < Vn){
          float bias = outb[v];
          lv[0]=acc.x+bias; lv[1]=acc.y+bias; lv[2]=acc.z+bias; lv[3]=acc.w+bias;
          #pragma unroll
          for (int m = 0; m < 4; ++m)
            dout[((long)(bq*4+m)*Tn + (t-1))*Vn + v] = lv[m];
        } else {
          lv[0]=lv[1]=lv[2]=lv[3]=-1e30f;
        }
        int tile = blk - 60;
        #pragma unroll
        for (int m = 0; m < 4; ++m){
          float bv = lv[m]; int bi = v;
          #pragma unroll
          for (int off = 32; off; off >>= 1){
            float ov = __shfl_down(bv, off, 64);
            int   oi = __shfl_down(bi, off, 64);
            if (ov > bv || (ov == bv && oi < bi)){ bv = ov; bi = oi; }
          }
          if (jl == 0){
            int b = bq*4 + m;
            ws[O_PMV + (long)b*NVT + tile] = bv;
            ((int*)(ws + O_PMI))[(long)b*NVT + tile] = bi;
          }
        }
      }
    }
    gg.sync();
    if (t == Tn) break;

    // ================= P2a: scores (224 blocks) + argmax finalize (32) =================
    {
      const int b = blk & 31, part = blk >> 5;
      if (part < 7){
        float* hid_s = scr;              // 512
        float* va_s  = scr + 512;        // 512
        hid_s[tid] = ws[O_HID + (long)b*Hn + tid];
        va_s[tid]  = vaw[tid];
        __syncthreads();
        const int w = tid >> 6, l = tid & 63;
        const int p0 = part*28;
        const float* eb = ws + O_ENC + (long)b*Pn*Hn;
        for (int p = p0 + w; p < p0 + 28; p += 8){
          const float* er = eb + (long)p*Hn;
          float4 e0 = *(const float4*)(er + l*4);
          float4 e1 = *(const float4*)(er + 256 + l*4);
          float4 h0 = *(const float4*)(hid_s + l*4);
          float4 h1 = *(const float4*)(hid_s + 256 + l*4);
          float4 v0 = *(const float4*)(va_s + l*4);
          float4 v1 = *(const float4*)(va_s + 256 + l*4);
          float s = fmaxf(h0.x+e0.x,0.f)*v0.x + fmaxf(h0.y+e0.y,0.f)*v0.y
                  + fmaxf(h0.z+e0.z,0.f)*v0.z + fmaxf(h0.w+e0.w,0.f)*v0.w
                  + fmaxf(h1.x+e1.x,0.f)*v1.x + fmaxf(h1.y+e1.y,0.f)*v1.y
                  + fmaxf(h1.z+e1.z,0.f)*v1.z + fmaxf(h1.w+e1.w,0.f)*v1.w;
          #pragma unroll
          for (int off = 32; off; off >>= 1) s += __shfl_down(s, off, 64);
          if (l == 0) ws[O_SVAL + (long)b*Pn + p] = s + vab[0];
        }
      } else {
        if (t == 0){
          if (tid == 0) ((int*)(ws + O_SEL))[b] = 1;     // SOS
        } else if (tid < 64){
          float bv = -1e30f; int bi = 0x7fffffff;
          for (int q = tid; q < NVT; q += 64){
            float cv = ws[O_PMV + (long)b*NVT + q];
            if (cv > bv){ bv = cv; bi = ((const int*)(ws + O_PMI))[(long)b*NVT + q]; }
          }
          #pragma unroll
          for (int off = 32; off; off >>= 1){
            float ov = __shfl_down(bv, off, 64);
            int   oi = __shfl_down(bi, off, 64);
            if (ov > bv || (ov == bv && oi < bi)){ bv = ov; bi = oi; }
          }
          if (tid == 0) ((int*)(ws + O_SEL))[b] = bi;
        }
      }
    }
    gg.sync();

    // ================= P2b: softmax + ctx + emb gather =================
    {
      const int b = blk & 31, fr = blk >> 5;
      float* s_s   = scr;          // 196
      float* wts_s = scr + 208;    // 196
      if (tid < Pn) s_s[tid] = ws[O_SVAL + (long)b*Pn + tid];
      __syncthreads();
      if (tid < 64){
        float m = -1e30f;
        for (int p = tid; p < Pn; p += 64) m = fmaxf(m, s_s[p]);
        #pragma unroll
        for (int off = 32; off; off >>= 1) m = fmaxf(m, __shfl_xor(m, off, 64));
        float sm = 0.f;
        for (int p = tid; p < Pn; p += 64) sm += expf(s_s[p] - m);
        #pragma unroll
        for (int off = 32; off; off >>= 1) sm += __shfl_xor(sm, off, 64);
        if (tid == 0){ scr[448] = m; scr[449] = 1.0f/sm; }
      }
      __syncthreads();
      {
        float mxv = scr[448], inv = scr[449];
        if (tid < Pn){
          float wv = expf(s_s[tid] - mxv) * inv;
          wts_s[tid] = wv;
          if (fr == 0)
            dout[(long)Bn*Tn*Vn + 2L*Bn*Hn + ((long)b*Tn + t)*Pn + tid] = wv;
        }
      }
      __syncthreads();
      const int pp = tid / 160, fl = tid - pp*160;
      float a = 0.f;
      if (tid < 480){
        const int p0 = pp*66, pn = (pp == 2) ? 64 : 66;
        const float* fp = feat + ((long)b*Pn + p0)*Fn + fr*160 + fl;
        for (int p = 0; p < pn; ++p) a += wts_s[p0 + p] * fp[(long)p*Fn];
        if (pp > 0) scr[512 + (pp-1)*160 + fl] = a;
      }
      __syncthreads();
      if (tid < 160){
        float tot = a + scr[512 + tid] + scr[672 + tid];
        int f = fr*160 + tid;
        tot *= ws[O_GT + (long)f*Bn + b];
        ws[O_XT + (long)(En + f)*Bn + b] = tot;
      }
      if (fr == 1){
        int row = (t == 0) ? 1 : ((const int*)(ws + O_SEL))[b];
        ws[O_XT + (long)tid*Bn + b] = emb[(long)row*En + tid];
      }
    }
    gg.sync();

    // ================= P3: Wih GEMM + LSTM update =================
    {
      const int c = tid & 7, ks = tid >> 3;      // 8 cols x 64 k-slices
      const int pc0 = blk*8;
      const float* wcol = ws + O_WIHT + pc0 + c;
      float acc[32];
      #pragma unroll
      for (int q = 0; q < 32; ++q) acc[q] = 0.f;
      const int kb = ks*28;
      #pragma unroll 4
      for (int i = 0; i < 28; ++i){
        const int k = kb + i;
        float w = wcol[(long)k*G4];
        const float4* x4 = (const float4*)(ws + O_XT + (long)k*Bn);
        float4 x0 = x4[0], x1 = x4[1], x2 = x4[2], x3 = x4[3];
        float4 x4v = x4[4], x5 = x4[5], x6 = x4[6], x7 = x4[7];
        acc[ 0]+=w*x0.x; acc[ 1]+=w*x0.y; acc[ 2]+=w*x0.z; acc[ 3]+=w*x0.w;
        acc[ 4]+=w*x1.x; acc[ 5]+=w*x1.y; acc[ 6]+=w*x1.z; acc[ 7]+=w*x1.w;
        acc[ 8]+=w*x2.x; acc[ 9]+=w*x2.y; acc[10]+=w*x2.z; acc[11]+=w*x2.w;
        acc[12]+=w*x3.x; acc[13]+=w*x3.y; acc[14]+=w*x3.z; acc[15]+=w*x3.w;
        acc[16]+=w*x4v.x; acc[17]+=w*x4v.y; acc[18]+=w*x4v.z; acc[19]+=w*x4v.w;
        acc[20]+=w*x5.x; acc[21]+=w*x5.y; acc[22]+=w*x5.z; acc[23]+=w*x5.w;
        acc[24]+=w*x6.x; acc[25]+=w*x6.y; acc[26]+=w*x6.z; acc[27]+=w*x6.w;
        acc[28]+=w*x7.x; acc[29]+=w*x7.y; acc[30]+=w*x7.z; acc[31]+=w*x7.w;
      }
      // reduce across 8 ks-groups within wave (lane = (ks&7)*8 + c)
      #pragma unroll
      for (int off = 8; off <= 32; off <<= 1){
        #pragma unroll
        for (int q = 0; q < 32; ++q) acc[q] += __shfl_xor(acc[q], off, 64);
      }
      const int lane = tid & 63, wv2 = tid >> 6;
      if (lane < 8){
        float* rb = scr + (wv2*8 + lane)*32;
        #pragma unroll
        for (int q = 0; q < 32; ++q) rb[q] = acc[q];
      }
      __syncthreads();
      if (tid < 256){
        int cc = tid >> 5, b = tid & 31;
        float s = 0.f;
        #pragma unroll
        for (int w2 = 0; w2 < 8; ++w2) s += scr[(w2*8 + cc)*32 + b];
        s += ws[O_XPT + (long)(pc0 + cc)*Bn + b];
        scr[2048 + cc*32 + b] = s;
      }
      __syncthreads();
      if (tid < 64){
        int il = tid >> 5, b = tid & 31;
        int i = blk*2 + il;
        float gi  = scr[2048 + (il*4+0)*32 + b];
        float gf  = scr[2048 + (il*4+1)*32 + b];
        float gg2 = scr[2048 + (il*4+2)*32 + b];
        float go  = scr[2048 + (il*4+3)*32 + b];
        float c_ = ws[O_C + (long)b*Hn + i];
        float cn = sigm(gf)*c_ + sigm(gi)*tanhf(gg2);
        float hn = sigm(go)*tanhf(cn);
        ws[O_C  + (long)b*Hn + i] = cn;
        ws[O_H  + (long)b*Hn + i] = hn;
        ws[O_HT + (long)i*Bn + b] = hn;
      }
    }
    gg.sync();
  }
}

} // anonymous namespace

extern "C" void kernel_launch(void* const* d_in, const int* in_sizes, int n_in,
                              void* d_out, int out_size, void* d_ws, size_t ws_size,
                              hipStream_t stream)
{
  (void)in_sizes; (void)n_in; (void)out_size; (void)ws_size;
  const float* feat = (const float*)d_in[0];
  const float* emb  = (const float*)d_in[3];
  const float* w1w  = (const float*)d_in[4];
  const float* w1b  = (const float*)d_in[5];
  const float* w2w  = (const float*)d_in[6];
  const float* w2b  = (const float*)d_in[7];
  const float* vaw  = (const float*)d_in[8];
  const float* vab  = (const float*)d_in[9];
  const float* wih  = (const float*)d_in[10];
  const float* whh  = (const float*)d_in[11];
  const float* bih  = (const float*)d_in[12];
  const float* bhh  = (const float*)d_in[13];
  const float* outw = (const float*)d_in[14];
  const float* outb = (const float*)d_in[15];
  const float* ihw  = (const float*)d_in[16];
  const float* ihb  = (const float*)d_in[17];
  const float* icw  = (const float*)d_in[18];
  const float* icb  = (const float*)d_in[19];
  const float* gw   = (const float*)d_in[20];
  const float* gb   = (const float*)d_in[21];
  float* ws  = (float*)d_ws;
  float* out = (float*)d_out;

  // setup: transposes of ihw/icw into ENC alias, mean, h0/c0
  k_tr_s<<<dim3(40,16),  256, 0, stream>>>(ihw,  ws + O_IHCT,       Hn, Fn, 1024);
  k_tr_s<<<dim3(40,16),  256, 0, stream>>>(icw,  ws + O_IHCT + 512, Hn, Fn, 1024);
  k_mean<<<160, 256, 0, stream>>>(feat, ws);
  k_h0c0<<<16, 512, 0, stream>>>(ihb, icb, ws);
  // persistent weight transposes
  k_tr_s<<<dim3(16,16),  256, 0, stream>>>(w1w,  ws + O_WCAT,          Hn, Hn, NCAT);
  k_tr_s<<<dim3(16,40),  256, 0, stream>>>(gw,   ws + O_WCAT + J_GATE, Fn, Hn, NCAT);
  k_tr_s<<<dim3(16,64),  256, 0, stream>>>(whh,  ws + O_WCAT + J_XP,   G4, Hn, NCAT);
  k_tr_s<<<dim3(16,313), 256, 0, stream>>>(outw, ws + O_WCAT + J_LOG,  Vn, Hn, NCAT);
  k_tr_wih<<<dim3(56,64), 256, 0, stream>>>(wih, ws);
  k_tr_s<<<dim3(40,16),  256, 0, stream>>>(w2w,  ws + O_W2T,           Hn, Fn, Hn);
  k_encproj<<<392, 512, 0, stream>>>(feat, w2b, ws);

  // the whole decode loop: one cooperative launch
  void* kargs[] = { (void*)&feat, (void*)&emb, (void*)&vaw, (void*)&vab,
                    (void*)&w1b, (void*)&gb, (void*)&bih, (void*)&bhh,
                    (void*)&outb, (void*)&ws, (void*)&out };
  hipLaunchCooperativeKernel((const void*)k_decode, dim3(NBLK), dim3(512),
                             kargs, 0, stream);
}

// Round 7
// 14585.121 us; speedup vs baseline: 1.1891x; 1.0271x over previous
//
#include <hip/hip_runtime.h>
#include <hip/hip_cooperative_groups.h>
#include <math.h>

#define RI __restrict__

namespace cg = cooperative_groups;

namespace {

constexpr int Hn=512, En=512, Vn=10000, Fn=1280, Pn=196, Bn=32, Tn=80;
constexpr int G4 = 2048, KX = 1792;
constexpr int NCAT = 13888;          // 512 hid + 1280 gate + 2048 xp + 10048 logits(pad)
constexpr int NVT = 157;
constexpr int J_GATE = 512, J_XP = 1792, J_LOG = 3840;
constexpr int NBLK = 256;

// ---- workspace layout (float indices) ----
constexpr long O_ENC  = 0;                           // [B*P][H]
constexpr long O_W2T  = O_ENC  + (long)Bn*Pn*Hn;     // [F][H]
constexpr long O_WCAT = O_W2T  + (long)Fn*Hn;        // [512][NCAT] (w1T|gwT|whhT|owT)
constexpr long O_WIHT = O_WCAT + (long)Hn*NCAT;      // [KX][2048] permuted cols (pc=i*4+g)
constexpr long O_H    = O_WIHT + (long)KX*G4;        // [B][H]
constexpr long O_HT   = O_H    + (long)Bn*Hn;        // [H][B]
constexpr long O_C    = O_HT   + (long)Hn*Bn;        // [B][H]
constexpr long O_HID  = O_C    + (long)Bn*Hn;        // [B][H]
constexpr long O_GT   = O_HID  + (long)Bn*Hn;        // [F][B]
constexpr long O_XPT  = O_GT   + (long)Fn*Bn;        // [2048 pc][B]
constexpr long O_XT   = O_XPT  + (long)G4*Bn;        // [KX][B]
constexpr long O_PMV  = O_XT   + (long)KX*Bn;        // [B][157]
constexpr long O_PMI  = O_PMV  + (long)Bn*NVT;       // [B][157] int
constexpr long O_SVAL = O_PMI  + (long)Bn*NVT;       // [B][196] raw scores
constexpr long O_SEL  = O_SVAL + (long)Bn*Pn;        // [B] int
// setup-only aliases inside O_ENC (consumed before k_encproj overwrites)
constexpr long O_IHCT  = O_ENC;                      // [1280][1024] (ihwT|icwT)
constexpr long O_MEANT = O_ENC + (long)Fn*1024;      // [F][B]

__device__ __forceinline__ float sigm(float x){ return 1.0f/(1.0f+expf(-x)); }
__device__ __forceinline__ void fma4(float4& a, const float4 x, const float w){
  a.x += w*x.x; a.y += w*x.y; a.z += w*x.z; a.w += w*x.w;
}

// ---------- transpose with dst stride: dst[c*S + r] = src[r*C + c] ----------
__global__ __launch_bounds__(256) void k_tr_s(const float* RI src, float* RI dst,
                                              int R, int C, int S){
  __shared__ float t[32][33];
  int tc0 = blockIdx.x*32, tr0 = blockIdx.y*32;
  int lx = threadIdx.x & 31, ly = threadIdx.x >> 5;
  for (int i = ly; i < 32; i += 8){
    int r = tr0 + i, c = tc0 + lx;
    t[i][lx] = (r < R && c < C) ? src[(long)r*C + c] : 0.f;
  }
  __syncthreads();
  for (int i = ly; i < 32; i += 8){
    int c = tc0 + i, r = tr0 + lx;
    if (c < C && r < R) dst[(long)c*S + r] = t[lx][i];
  }
}

// ---------- wih transpose, gate-interleaved cols: WIHT[k][pc]=wih[j][k], pc=(j&511)*4+(j>>9)
__global__ __launch_bounds__(256) void k_tr_wih(const float* RI src, float* RI ws){
  __shared__ float t[32][33];
  int tk0 = blockIdx.x*32, tj0 = blockIdx.y*32;
  int lx = threadIdx.x & 31, ly = threadIdx.x >> 5;
  for (int i = ly; i < 32; i += 8){
    int j = tj0 + i, k = tk0 + lx;
    t[i][lx] = src[(long)j*KX + k];
  }
  __syncthreads();
  for (int i = ly; i < 32; i += 8){
    int k = tk0 + i, j = tj0 + lx;
    int pc = ((j & 511) << 2) | (j >> 9);
    ws[O_WIHT + (long)k*G4 + pc] = t[lx][i];
  }
}

// ---------- meanT[f][b] ----------
__global__ __launch_bounds__(256) void k_mean(const float* RI feat, float* RI ws){
  int blk = blockIdx.x;             // 160 = 32 b x 5 f-tiles
  int b = blk / 5, ft = blk % 5;
  int f = ft*256 + threadIdx.x;
  float s = 0.f;
  const float* fp = feat + (long)b*Pn*Fn + f;
  for (int p = 0; p < Pn; ++p) s += fp[(long)p*Fn];
  ws[O_MEANT + (long)f*Bn + b] = s * (1.0f/Pn);
}

// ---------- h0,c0 ----------
__global__ __launch_bounds__(512) void k_h0c0(const float* RI ihb, const float* RI icb,
                                              float* RI ws){
  int tid = threadIdx.x;
  int jl = tid & 63, bq = tid >> 6;
  int j = blockIdx.x*64 + jl;
  const float* wp = ws + O_IHCT + j;
  const float* xp = ws + O_MEANT + bq*4;
  float4 acc = make_float4(0,0,0,0);
  for (int k = 0; k < Fn; ++k){
    float w = wp[(long)k*1024];
    float4 x = *(const float4*)(xp + (long)k*Bn);
    fma4(acc, x, w);
  }
  float va[4] = {acc.x, acc.y, acc.z, acc.w};
  if (j < Hn){
    float bias = ihb[j];
    #pragma unroll
    for (int m = 0; m < 4; ++m){
      int b = bq*4 + m;
      float v = va[m] + bias;
      ws[O_H  + (long)b*Hn + j] = v;
      ws[O_HT + (long)j*Bn + b] = v;
    }
  } else {
    int j2 = j - Hn;
    float bias = icb[j2];
    #pragma unroll
    for (int m = 0; m < 4; ++m)
      ws[O_C + (long)(bq*4+m)*Hn + j2] = va[m] + bias;
  }
}

// ---------- enc_proj: 392 blocks = 98 rt x 4 ct; 64 rows x 128 j per block ----------
__global__ __launch_bounds__(512) void k_encproj(const float* RI feat, const float* RI w2b,
                                                 float* RI ws){
  __shared__ __align__(16) float xs[64*65];
  const int blk = blockIdx.x;
  const int rt = blk >> 2, ct = blk & 3;
  const int r0 = rt*64, j0 = ct*128;
  const int tid = threadIdx.x;
  const int jq = tid & 31, rg = tid >> 5;
  const int rw = tid >> 3, kc = (tid & 7)*8;
  const float* w2t = ws + O_W2T + j0 + jq*4;
  float4 a0 = make_float4(0,0,0,0), a1 = a0, a2 = a0, a3 = a0;
  for (int k0 = 0; k0 < Fn; k0 += 64){
    __syncthreads();
    {
      const float* fp = feat + (long)(r0+rw)*Fn + k0 + kc;
      float4 v0 = *(const float4*)(fp);
      float4 v1 = *(const float4*)(fp + 4);
      float* xr = xs + rw*65 + kc;
      xr[0]=v0.x; xr[1]=v0.y; xr[2]=v0.z; xr[3]=v0.w;
      xr[4]=v1.x; xr[5]=v1.y; xr[6]=v1.z; xr[7]=v1.w;
    }
    __syncthreads();
    #pragma unroll 4
    for (int kk = 0; kk < 64; ++kk){
      float4 w = *(const float4*)(w2t + (long)(k0+kk)*Hn);
      const float* xp = xs + (rg*4)*65 + kk;
      fma4(a0, w, xp[0]);
      fma4(a1, w, xp[65]);
      fma4(a2, w, xp[130]);
      fma4(a3, w, xp[195]);
    }
  }
  float4 b4 = *(const float4*)(w2b + j0 + jq*4);
  float4 out[4] = {a0,a1,a2,a3};
  #pragma unroll
  for (int m = 0; m < 4; ++m){
    long r = r0 + rg*4 + m;
    float4 o = out[m];
    o.x += b4.x; o.y += b4.y; o.z += b4.z; o.w += b4.w;
    *(float4*)(ws + O_ENC + r*Hn + j0 + jq*4) = o;
  }
}

// ---------- the whole 80-step decode: ONE cooperative kernel ----------
// 256 blocks x 512 threads, 1 block/CU, WCAT slice pinned in LDS (128 KB).
// NOTE: no min-wave clamp -> compiler may use up to 256 VGPR (1 blk/CU anyway).
__global__ __launch_bounds__(512) void k_decode(
    const float* RI feat, const float* RI emb, const float* RI vaw, const float* RI vab,
    const float* RI w1b, const float* RI gb, const float* RI bih, const float* RI bhh,
    const float* RI outb, float* RI ws, float* RI dout)
{
  __shared__ __align__(16) float wlds[512*64];   // 128 KB pinned WCAT slice [k][64 j]
  __shared__ __align__(16) float scr[3072];      // 12 KB phase scratch
  cg::grid_group gg = cg::this_grid();
  const int blk = blockIdx.x, tid = threadIdx.x;
  const int jl = tid & 63, bq = tid >> 6;

  // ---- one-time: stage this block's WCAT slice into LDS ----
  if (blk < 217){
    const float* wg = ws + O_WCAT + blk*64;
    for (int idx = tid; idx < 512*64; idx += 512){
      int k = idx >> 6, j = idx & 63;
      wlds[idx] = wg[(long)k*NCAT + j];
    }
  }
  __syncthreads();

  for (int t = 0; t <= Tn; ++t){
    // ================= P1: unified h-GEMM from LDS weights =================
    if (t == Tn && blk < 2){
      const float* src = ws + (blk == 0 ? O_H : O_C);
      float* dst = dout + (long)Bn*Tn*Vn + (long)blk*Bn*Hn;
      for (int i = tid; i < Bn*Hn; i += 512) dst[i] = src[i];
    }
    bool doP1 = (t == Tn) ? (blk >= 60 && blk < 217)
                          : (blk < 217 && !(t == 0 && blk >= 60));
    if (doP1){
      const float4* HT4 = (const float4*)(ws + O_HT);
      float4 accA = make_float4(0,0,0,0), accB = make_float4(0,0,0,0);
      #pragma unroll 4
      for (int k = 0; k < Hn; k += 2){
        float w0 = wlds[(k << 6) + jl];
        float w1 = wlds[((k+1) << 6) + jl];
        float4 x0 = HT4[(k << 3) + bq];
        float4 x1 = HT4[((k+1) << 3) + bq];
        fma4(accA, x0, w0);
        fma4(accB, x1, w1);
      }
      float4 acc = make_float4(accA.x+accB.x, accA.y+accB.y,
                               accA.z+accB.z, accA.w+accB.w);
      const int j = blk*64 + jl;
      if (blk < 8){                      // hid
        float bias = w1b[j];
        ws[O_HID + (long)(bq*4+0)*Hn + j] = acc.x + bias;
        ws[O_HID + (long)(bq*4+1)*Hn + j] = acc.y + bias;
        ws[O_HID + (long)(bq*4+2)*Hn + j] = acc.z + bias;
        ws[O_HID + (long)(bq*4+3)*Hn + j] = acc.w + bias;
      } else if (blk < 28){              // gate (sigmoid)
        int f = j - J_GATE;
        float bias = gb[f];
        float4 g = make_float4(sigm(acc.x+bias), sigm(acc.y+bias),
                               sigm(acc.z+bias), sigm(acc.w+bias));
        *(float4*)(ws + O_GT + (long)f*Bn + bq*4) = g;
      } else if (blk < 60){              // xpart (permuted col layout)
        int j2 = j - J_XP;
        int pc = ((j2 & 511) << 2) | (j2 >> 9);
        float bias = bih[j2] + bhh[j2];
        float4 a = make_float4(acc.x+bias, acc.y+bias, acc.z+bias, acc.w+bias);
        *(float4*)(ws + O_XPT + (long)pc*Bn + bq*4) = a;
      } else {                           // logits_{t-1} + argmax partials
        int v = j - J_LOG;
        float lv[4];
        if (v < Vn){
          float bias = outb[v];
          lv[0]=acc.x+bias; lv[1]=acc.y+bias; lv[2]=acc.z+bias; lv[3]=acc.w+bias;
          #pragma unroll
          for (int m = 0; m < 4; ++m)
            dout[((long)(bq*4+m)*Tn + (t-1))*Vn + v] = lv[m];
        } else {
          lv[0]=lv[1]=lv[2]=lv[3]=-1e30f;
        }
        int tile = blk - 60;
        #pragma unroll
        for (int m = 0; m < 4; ++m){
          float bv = lv[m]; int bi = v;
          #pragma unroll
          for (int off = 32; off; off >>= 1){
            float ov = __shfl_down(bv, off, 64);
            int   oi = __shfl_down(bi, off, 64);
            if (ov > bv || (ov == bv && oi < bi)){ bv = ov; bi = oi; }
          }
          if (jl == 0){
            int b = bq*4 + m;
            ws[O_PMV + (long)b*NVT + tile] = bv;
            ((int*)(ws + O_PMI))[(long)b*NVT + tile] = bi;
          }
        }
      }
    }
    gg.sync();
    if (t == Tn) break;

    // ================= P2a: scores (224 blocks) + argmax finalize (32) =================
    {
      const int b = blk & 31, part = blk >> 5;
      if (part < 7){
        float* hid_s = scr;              // 512
        float* va_s  = scr + 512;        // 512
        hid_s[tid] = ws[O_HID + (long)b*Hn + tid];
        va_s[tid]  = vaw[tid];
        __syncthreads();
        const int w = tid >> 6, l = tid & 63;
        const int p0 = part*28;
        const float* eb = ws + O_ENC + (long)b*Pn*Hn;
        #pragma unroll 2
        for (int p = p0 + w; p < p0 + 28; p += 8){
          const float* er = eb + (long)p*Hn;
          float4 e0 = *(const float4*)(er + l*4);
          float4 e1 = *(const float4*)(er + 256 + l*4);
          float4 h0 = *(const float4*)(hid_s + l*4);
          float4 h1 = *(const float4*)(hid_s + 256 + l*4);
          float4 v0 = *(const float4*)(va_s + l*4);
          float4 v1 = *(const float4*)(va_s + 256 + l*4);
          float s = fmaxf(h0.x+e0.x,0.f)*v0.x + fmaxf(h0.y+e0.y,0.f)*v0.y
                  + fmaxf(h0.z+e0.z,0.f)*v0.z + fmaxf(h0.w+e0.w,0.f)*v0.w
                  + fmaxf(h1.x+e1.x,0.f)*v1.x + fmaxf(h1.y+e1.y,0.f)*v1.y
                  + fmaxf(h1.z+e1.z,0.f)*v1.z + fmaxf(h1.w+e1.w,0.f)*v1.w;
          #pragma unroll
          for (int off = 32; off; off >>= 1) s += __shfl_down(s, off, 64);
          if (l == 0) ws[O_SVAL + (long)b*Pn + p] = s + vab[0];
        }
      } else {
        if (t == 0){
          if (tid == 0) ((int*)(ws + O_SEL))[b] = 1;     // SOS
        } else if (tid < 64){
          float bv = -1e30f; int bi = 0x7fffffff;
          #pragma unroll 2
          for (int q = tid; q < NVT; q += 64){
            float cv = ws[O_PMV + (long)b*NVT + q];
            if (cv > bv){ bv = cv; bi = ((const int*)(ws + O_PMI))[(long)b*NVT + q]; }
          }
          #pragma unroll
          for (int off = 32; off; off >>= 1){
            float ov = __shfl_down(bv, off, 64);
            int   oi = __shfl_down(bi, off, 64);
            if (ov > bv || (ov == bv && oi < bi)){ bv = ov; bi = oi; }
          }
          if (tid == 0) ((int*)(ws + O_SEL))[b] = bi;
        }
      }
    }
    gg.sync();

    // ================= P2b: softmax + ctx + emb gather =================
    {
      const int b = blk & 31, fr = blk >> 5;
      float* s_s   = scr;          // 196
      float* wts_s = scr + 208;    // 196
      if (tid < Pn) s_s[tid] = ws[O_SVAL + (long)b*Pn + tid];
      __syncthreads();
      if (tid < 64){
        float m = -1e30f;
        for (int p = tid; p < Pn; p += 64) m = fmaxf(m, s_s[p]);
        #pragma unroll
        for (int off = 32; off; off >>= 1) m = fmaxf(m, __shfl_xor(m, off, 64));
        float sm = 0.f;
        for (int p = tid; p < Pn; p += 64) sm += expf(s_s[p] - m);
        #pragma unroll
        for (int off = 32; off; off >>= 1) sm += __shfl_xor(sm, off, 64);
        if (tid == 0){ scr[448] = m; scr[449] = 1.0f/sm; }
      }
      __syncthreads();
      {
        float mxv = scr[448], inv = scr[449];
        if (tid < Pn){
          float wv = expf(s_s[tid] - mxv) * inv;
          wts_s[tid] = wv;
          if (fr == 0)
            dout[(long)Bn*Tn*Vn + 2L*Bn*Hn + ((long)b*Tn + t)*Pn + tid] = wv;
        }
      }
      __syncthreads();
      const int pp = tid / 160, fl = tid - pp*160;
      float a = 0.f;
      if (tid < 480){
        const int p0 = pp*66, pn = (pp == 2) ? 64 : 66;
        const float* fp = feat + ((long)b*Pn + p0)*Fn + fr*160 + fl;
        const float* wl = wts_s + p0;
        float a0=0.f, a1=0.f, a2=0.f, a3=0.f;
        int p = 0;
        #pragma unroll 2
        for (; p + 4 <= pn; p += 4){
          float w0 = wl[p+0], w1 = wl[p+1], w2 = wl[p+2], w3 = wl[p+3];
          float v0 = fp[(long)(p+0)*Fn];
          float v1 = fp[(long)(p+1)*Fn];
          float v2 = fp[(long)(p+2)*Fn];
          float v3 = fp[(long)(p+3)*Fn];
          a0 += w0*v0; a1 += w1*v1; a2 += w2*v2; a3 += w3*v3;
        }
        for (; p < pn; ++p) a0 += wl[p] * fp[(long)p*Fn];
        a = (a0 + a1) + (a2 + a3);
        if (pp > 0) scr[512 + (pp-1)*160 + fl] = a;
      }
      __syncthreads();
      if (tid < 160){
        float tot = a + scr[512 + tid] + scr[672 + tid];
        int f = fr*160 + tid;
        tot *= ws[O_GT + (long)f*Bn + b];
        ws[O_XT + (long)(En + f)*Bn + b] = tot;
      }
      if (fr == 1){
        int row = (t == 0) ? 1 : ((const int*)(ws + O_SEL))[b];
        ws[O_XT + (long)tid*Bn + b] = emb[(long)row*En + tid];
      }
    }
    gg.sync();

    // ================= P3: Wih GEMM + LSTM update =================
    {
      const int c = tid & 7, ks = tid >> 3;      // 8 cols x 64 k-slices
      const int pc0 = blk*8;
      const float* wcol = ws + O_WIHT + pc0 + c;
      float acc[32];
      #pragma unroll
      for (int q = 0; q < 32; ++q) acc[q] = 0.f;
      const int kb = ks*28;
      #pragma unroll 2
      for (int i = 0; i < 28; i += 2){
        const int k = kb + i;
        float wA = wcol[(long)k*G4];
        float wB = wcol[(long)(k+1)*G4];
        const float4* xa = (const float4*)(ws + O_XT + (long)k*Bn);
        const float4* xb = (const float4*)(ws + O_XT + (long)(k+1)*Bn);
        float4 A0=xa[0],A1=xa[1],A2=xa[2],A3=xa[3],A4=xa[4],A5=xa[5],A6=xa[6],A7=xa[7];
        float4 B0=xb[0],B1=xb[1],B2=xb[2],B3=xb[3],B4=xb[4],B5=xb[5],B6=xb[6],B7=xb[7];
        acc[ 0]+=wA*A0.x; acc[ 1]+=wA*A0.y; acc[ 2]+=wA*A0.z; acc[ 3]+=wA*A0.w;
        acc[ 4]+=wA*A1.x; acc[ 5]+=wA*A1.y; acc[ 6]+=wA*A1.z; acc[ 7]+=wA*A1.w;
        acc[ 8]+=wA*A2.x; acc[ 9]+=wA*A2.y; acc[10]+=wA*A2.z; acc[11]+=wA*A2.w;
        acc[12]+=wA*A3.x; acc[13]+=wA*A3.y; acc[14]+=wA*A3.z; acc[15]+=wA*A3.w;
        acc[16]+=wA*A4.x; acc[17]+=wA*A4.y; acc[18]+=wA*A4.z; acc[19]+=wA*A4.w;
        acc[20]+=wA*A5.x; acc[21]+=wA*A5.y; acc[22]+=wA*A5.z; acc[23]+=wA*A5.w;
        acc[24]+=wA*A6.x; acc[25]+=wA*A6.y; acc[26]+=wA*A6.z; acc[27]+=wA*A6.w;
        acc[28]+=wA*A7.x; acc[29]+=wA*A7.y; acc[30]+=wA*A7.z; acc[31]+=wA*A7.w;
        acc[ 0]+=wB*B0.x; acc[ 1]+=wB*B0.y; acc[ 2]+=wB*B0.z; acc[ 3]+=wB*B0.w;
        acc[ 4]+=wB*B1.x; acc[ 5]+=wB*B1.y; acc[ 6]+=wB*B1.z; acc[ 7]+=wB*B1.w;
        acc[ 8]+=wB*B2.x; acc[ 9]+=wB*B2.y; acc[10]+=wB*B2.z; acc[11]+=wB*B2.w;
        acc[12]+=wB*B3.x; acc[13]+=wB*B3.y; acc[14]+=wB*B3.z; acc[15]+=wB*B3.w;
        acc[16]+=wB*B4.x; acc[17]+=wB*B4.y; acc[18]+=wB*B4.z; acc[19]+=wB*B4.w;
        acc[20]+=wB*B5.x; acc[21]+=wB*B5.y; acc[22]+=wB*B5.z; acc[23]+=wB*B5.w;
        acc[24]+=wB*B6.x; acc[25]+=wB*B6.y; acc[26]+=wB*B6.z; acc[27]+=wB*B6.w;
        acc[28]+=wB*B7.x; acc[29]+=wB*B7.y; acc[30]+=wB*B7.z; acc[31]+=wB*B7.w;
      }
      // reduce across 8 ks-groups within wave (lane = (ks&7)*8 + c)
      #pragma unroll
      for (int off = 8; off <= 32; off <<= 1){
        #pragma unroll
        for (int q = 0; q < 32; ++q) acc[q] += __shfl_xor(acc[q], off, 64);
      }
      const int lane = tid & 63, wv2 = tid >> 6;
      if (lane < 8){
        float* rb = scr + (wv2*8 + lane)*32;
        #pragma unroll
        for (int q = 0; q < 32; ++q) rb[q] = acc[q];
      }
      __syncthreads();
      if (tid < 256){
        int cc = tid >> 5, b = tid & 31;
        float s = 0.f;
        #pragma unroll
        for (int w2 = 0; w2 < 8; ++w2) s += scr[(w2*8 + cc)*32 + b];
        s += ws[O_XPT + (long)(pc0 + cc)*Bn + b];
        scr[2048 + cc*32 + b] = s;
      }
      __syncthreads();
      if (tid < 64){
        int il = tid >> 5, b = tid & 31;
        int i = blk*2 + il;
        float gi  = scr[2048 + (il*4+0)*32 + b];
        float gf  = scr[2048 + (il*4+1)*32 + b];
        float gg2 = scr[2048 + (il*4+2)*32 + b];
        float go  = scr[2048 + (il*4+3)*32 + b];
        float c_ = ws[O_C + (long)b*Hn + i];
        float cn = sigm(gf)*c_ + sigm(gi)*tanhf(gg2);
        float hn = sigm(go)*tanhf(cn);
        ws[O_C  + (long)b*Hn + i] = cn;
        ws[O_H  + (long)b*Hn + i] = hn;
        ws[O_HT + (long)i*Bn + b] = hn;
      }
    }
    gg.sync();
  }
}

} // anonymous namespace

extern "C" void kernel_launch(void* const* d_in, const int* in_sizes, int n_in,
                              void* d_out, int out_size, void* d_ws, size_t ws_size,
                              hipStream_t stream)
{
  (void)in_sizes; (void)n_in; (void)out_size; (void)ws_size;
  const float* feat = (const float*)d_in[0];
  const float* emb  = (const float*)d_in[3];
  const float* w1w  = (const float*)d_in[4];
  const float* w1b  = (const float*)d_in[5];
  const float* w2w  = (const float*)d_in[6];
  const float* w2b  = (const float*)d_in[7];
  const float* vaw  = (const float*)d_in[8];
  const float* vab  = (const float*)d_in[9];
  const float* wih  = (const float*)d_in[10];
  const float* whh  = (const float*)d_in[11];
  const float* bih  = (const float*)d_in[12];
  const float* bhh  = (const float*)d_in[13];
  const float* outw = (const float*)d_in[14];
  const float* outb = (const float*)d_in[15];
  const float* ihw  = (const float*)d_in[16];
  const float* ihb  = (const float*)d_in[17];
  const float* icw  = (const float*)d_in[18];
  const float* icb  = (const float*)d_in[19];
  const float* gw   = (const float*)d_in[20];
  const float* gb   = (const float*)d_in[21];
  float* ws  = (float*)d_ws;
  float* out = (float*)d_out;

  // setup: transposes of ihw/icw into ENC alias, mean, h0/c0
  k_tr_s<<<dim3(40,16),  256, 0, stream>>>(ihw,  ws + O_IHCT,       Hn, Fn, 1024);
  k_tr_s<<<dim3(40,16),  256, 0, stream>>>(icw,  ws + O_IHCT + 512, Hn, Fn, 1024);
  k_mean<<<160, 256, 0, stream>>>(feat, ws);
  k_h0c0<<<16, 512, 0, stream>>>(ihb, icb, ws);
  // persistent weight transposes
  k_tr_s<<<dim3(16,16),  256, 0, stream>>>(w1w,  ws + O_WCAT,          Hn, Hn, NCAT);
  k_tr_s<<<dim3(16,40),  256, 0, stream>>>(gw,   ws + O_WCAT + J_GATE, Fn, Hn, NCAT);
  k_tr_s<<<dim3(16,64),  256, 0, stream>>>(whh,  ws + O_WCAT + J_XP,   G4, Hn, NCAT);
  k_tr_s<<<dim3(16,313), 256, 0, stream>>>(outw, ws + O_WCAT + J_LOG,  Vn, Hn, NCAT);
  k_tr_wih<<<dim3(56,64), 256, 0, stream>>>(wih, ws);
  k_tr_s<<<dim3(40,16),  256, 0, stream>>>(w2w,  ws + O_W2T,           Hn, Fn, Hn);
  k_encproj<<<392, 512, 0, stream>>>(feat, w2b, ws);

  // the whole decode loop: one cooperative launch
  void* kargs[] = { (void*)&feat, (void*)&emb, (void*)&vaw, (void*)&vab,
                    (void*)&w1b, (void*)&gb, (void*)&bih, (void*)&bhh,
                    (void*)&outb, (void*)&ws, (void*)&out };
  hipLaunchCooperativeKernel((const void*)k_decode, dim3(NBLK), dim3(512),
                             kargs, 0, stream);
}

// Round 8
// 11374.274 us; speedup vs baseline: 1.5248x; 1.2823x over previous
//
#include <hip/hip_runtime.h>
#include <hip/hip_cooperative_groups.h>
#include <math.h>

#define RI __restrict__

namespace {

constexpr int Hn=512, En=512, Vn=10000, Fn=1280, Pn=196, Bn=32, Tn=80;
constexpr int G4 = 2048, KX = 1792;
constexpr int NCAT = 13888;          // 512 hid + 1280 gate + 2048 xp + 10048 logits(pad)
constexpr int NVT = 157;
constexpr int J_GATE = 512, J_XP = 1792, J_LOG = 3840;
constexpr int NBLK = 256;

// ---- workspace layout (float indices) ----
constexpr long O_ENC  = 0;                           // [B*P][H]
constexpr long O_W2T  = O_ENC  + (long)Bn*Pn*Hn;     // [F][H]
constexpr long O_WCAT = O_W2T  + (long)Fn*Hn;        // [512][NCAT] (w1T|gwT|whhT|owT)
constexpr long O_WIHT = O_WCAT + (long)Hn*NCAT;      // [KX][2048] permuted cols (pc=i*4+g)
constexpr long O_H    = O_WIHT + (long)KX*G4;        // [B][H] (setup only)
constexpr long O_HT   = O_H    + (long)Bn*Hn;        // [H][B]  ** coherent **
constexpr long O_C    = O_HT   + (long)Hn*Bn;        // [B][H]  block-private in decode
constexpr long O_HID  = O_C    + (long)Bn*Hn;        // [B][H]  ** coherent **
constexpr long O_GT   = O_HID  + (long)Bn*Hn;        // [F][B]  ** coherent **
constexpr long O_XPT  = O_GT   + (long)Fn*Bn;        // [2048 pc][B] ** coherent **
constexpr long O_XT   = O_XPT  + (long)G4*Bn;        // [KX][B] ** coherent **
constexpr long O_PMV  = O_XT   + (long)KX*Bn;        // [B][157] ** coherent **
constexpr long O_PMI  = O_PMV  + (long)Bn*NVT;       // [B][157] int ** coherent **
constexpr long O_CNT  = O_PMI  + (long)Bn*NVT + 64;  // 3 barrier counters (128B apart)
// setup-only aliases inside O_ENC (consumed before k_encproj overwrites)
constexpr long O_IHCT  = O_ENC;                      // [1280][1024] (ihwT|icwT)
constexpr long O_MEANT = O_ENC + (long)Fn*1024;      // [F][B]

__device__ __forceinline__ float sigm(float x){ return 1.0f/(1.0f+expf(-x)); }
__device__ __forceinline__ void fma4(float4& a, const float4 x, const float w){
  a.x += w*x.x; a.y += w*x.y; a.z += w*x.z; a.w += w*x.w;
}
// coherent (agent-scope, L2-bypassing) accessors
__device__ __forceinline__ float ldc(const float* p){
  return __hip_atomic_load(p, __ATOMIC_RELAXED, __HIP_MEMORY_SCOPE_AGENT);
}
__device__ __forceinline__ void stc(float* p, float v){
  __hip_atomic_store(p, v, __ATOMIC_RELAXED, __HIP_MEMORY_SCOPE_AGENT);
}
__device__ __forceinline__ int ldci(const int* p){
  return __hip_atomic_load(p, __ATOMIC_RELAXED, __HIP_MEMORY_SCOPE_AGENT);
}
__device__ __forceinline__ void stci(int* p, int v){
  __hip_atomic_store(p, v, __ATOMIC_RELAXED, __HIP_MEMORY_SCOPE_AGENT);
}

// relaxed counter barrier: no acquire/release fence -> L2 stays warm.
// __syncthreads() before arrival drains each thread's vmcnt (stores complete).
__device__ __forceinline__ void gbar(unsigned* cnt, unsigned target){
  __syncthreads();
  if (threadIdx.x == 0){
    __hip_atomic_fetch_add(cnt, 1u, __ATOMIC_RELAXED, __HIP_MEMORY_SCOPE_AGENT);
    while (__hip_atomic_load(cnt, __ATOMIC_RELAXED, __HIP_MEMORY_SCOPE_AGENT) < target)
      __builtin_amdgcn_s_sleep(2);
  }
  __syncthreads();
}

// ---------- transpose with dst stride: dst[c*S + r] = src[r*C + c] ----------
__global__ __launch_bounds__(256) void k_tr_s(const float* RI src, float* RI dst,
                                              int R, int C, int S){
  __shared__ float t[32][33];
  int tc0 = blockIdx.x*32, tr0 = blockIdx.y*32;
  int lx = threadIdx.x & 31, ly = threadIdx.x >> 5;
  for (int i = ly; i < 32; i += 8){
    int r = tr0 + i, c = tc0 + lx;
    t[i][lx] = (r < R && c < C) ? src[(long)r*C + c] : 0.f;
  }
  __syncthreads();
  for (int i = ly; i < 32; i += 8){
    int c = tc0 + i, r = tr0 + lx;
    if (c < C && r < R) dst[(long)c*S + r] = t[lx][i];
  }
}

// ---------- wih transpose, gate-interleaved cols: WIHT[k][pc]=wih[j][k], pc=(j&511)*4+(j>>9)
__global__ __launch_bounds__(256) void k_tr_wih(const float* RI src, float* RI ws){
  __shared__ float t[32][33];
  int tk0 = blockIdx.x*32, tj0 = blockIdx.y*32;
  int lx = threadIdx.x & 31, ly = threadIdx.x >> 5;
  for (int i = ly; i < 32; i += 8){
    int j = tj0 + i, k = tk0 + lx;
    t[i][lx] = src[(long)j*KX + k];
  }
  __syncthreads();
  for (int i = ly; i < 32; i += 8){
    int k = tk0 + i, j = tj0 + lx;
    int pc = ((j & 511) << 2) | (j >> 9);
    ws[O_WIHT + (long)k*G4 + pc] = t[lx][i];
  }
}

// ---------- meanT[f][b] ----------
__global__ __launch_bounds__(256) void k_mean(const float* RI feat, float* RI ws){
  int blk = blockIdx.x;             // 160 = 32 b x 5 f-tiles
  int b = blk / 5, ft = blk % 5;
  int f = ft*256 + threadIdx.x;
  float s = 0.f;
  const float* fp = feat + (long)b*Pn*Fn + f;
  for (int p = 0; p < Pn; ++p) s += fp[(long)p*Fn];
  ws[O_MEANT + (long)f*Bn + b] = s * (1.0f/Pn);
}

// ---------- h0,c0 ----------
__global__ __launch_bounds__(512) void k_h0c0(const float* RI ihb, const float* RI icb,
                                              float* RI ws){
  int tid = threadIdx.x;
  int jl = tid & 63, bq = tid >> 6;
  int j = blockIdx.x*64 + jl;
  const float* wp = ws + O_IHCT + j;
  const float* xp = ws + O_MEANT + bq*4;
  float4 acc = make_float4(0,0,0,0);
  for (int k = 0; k < Fn; ++k){
    float w = wp[(long)k*1024];
    float4 x = *(const float4*)(xp + (long)k*Bn);
    fma4(acc, x, w);
  }
  float va[4] = {acc.x, acc.y, acc.z, acc.w};
  if (j < Hn){
    float bias = ihb[j];
    #pragma unroll
    for (int m = 0; m < 4; ++m){
      int b = bq*4 + m;
      ws[O_HT + (long)j*Bn + b] = va[m] + bias;
    }
  } else {
    int j2 = j - Hn;
    float bias = icb[j2];
    #pragma unroll
    for (int m = 0; m < 4; ++m)
      ws[O_C + (long)(bq*4+m)*Hn + j2] = va[m] + bias;
  }
}

// ---------- enc_proj: 392 blocks = 98 rt x 4 ct; 64 rows x 128 j per block ----------
__global__ __launch_bounds__(512) void k_encproj(const float* RI feat, const float* RI w2b,
                                                 float* RI ws){
  __shared__ __align__(16) float xs[64*65];
  const int blk = blockIdx.x;
  const int rt = blk >> 2, ct = blk & 3;
  const int r0 = rt*64, j0 = ct*128;
  const int tid = threadIdx.x;
  const int jq = tid & 31, rg = tid >> 5;
  const int rw = tid >> 3, kc = (tid & 7)*8;
  const float* w2t = ws + O_W2T + j0 + jq*4;
  float4 a0 = make_float4(0,0,0,0), a1 = a0, a2 = a0, a3 = a0;
  for (int k0 = 0; k0 < Fn; k0 += 64){
    __syncthreads();
    {
      const float* fp = feat + (long)(r0+rw)*Fn + k0 + kc;
      float4 v0 = *(const float4*)(fp);
      float4 v1 = *(const float4*)(fp + 4);
      float* xr = xs + rw*65 + kc;
      xr[0]=v0.x; xr[1]=v0.y; xr[2]=v0.z; xr[3]=v0.w;
      xr[4]=v1.x; xr[5]=v1.y; xr[6]=v1.z; xr[7]=v1.w;
    }
    __syncthreads();
    #pragma unroll 4
    for (int kk = 0; kk < 64; ++kk){
      float4 w = *(const float4*)(w2t + (long)(k0+kk)*Hn);
      const float* xp = xs + (rg*4)*65 + kk;
      fma4(a0, w, xp[0]);
      fma4(a1, w, xp[65]);
      fma4(a2, w, xp[130]);
      fma4(a3, w, xp[195]);
    }
  }
  float4 b4 = *(const float4*)(w2b + j0 + jq*4);
  float4 out[4] = {a0,a1,a2,a3};
  #pragma unroll
  for (int m = 0; m < 4; ++m){
    long r = r0 + rg*4 + m;
    float4 o = out[m];
    o.x += b4.x; o.y += b4.y; o.z += b4.z; o.w += b4.w;
    *(float4*)(ws + O_ENC + r*Hn + j0 + jq*4) = o;
  }
}

// ---------- the whole 80-step decode: ONE cooperative kernel, relaxed barriers ----------
__global__ __launch_bounds__(512) void k_decode(
    const float* RI feat, const float* RI emb, const float* RI vaw, const float* RI vab,
    const float* RI w1b, const float* RI gb, const float* RI bih, const float* RI bhh,
    const float* RI outb, float* RI ws, float* RI dout)
{
  __shared__ __align__(16) float wlds[32768];    // 128 KB pinned WCAT slice [k][64 j]
  __shared__ __align__(16) float sbuf[4864];     // 19 KB phase scratch (P2 / P3 overlay)
  const int blk = blockIdx.x, tid = threadIdx.x;
  const int jl = tid & 63, bq = tid >> 6;
  unsigned* cnt = (unsigned*)(ws + O_CNT);

  // ---- one-time: stage this block's WCAT slice into LDS ----
  if (blk < 217){
    const float* wg = ws + O_WCAT + blk*64;
    for (int idx = tid; idx < 512*64; idx += 512){
      int k = idx >> 6, j = idx & 63;
      wlds[idx] = wg[(long)k*NCAT + j];
    }
  }
  __syncthreads();

  for (int t = 0; t <= Tn; ++t){
    // ================= P1: unified h-GEMM (LDS weights, reg+shfl HT) =================
    bool p1act;
    if (t == Tn)      p1act = (blk >= 60 && blk < 217);
    else if (t == 0)  p1act = (blk < 60);
    else              p1act = (blk < 217);
    if (p1act){
      // stage HT[k][bq*4..+4] for k in [jl*8, jl*8+8) -> 32 regs (coherent loads)
      float xs[32];
      #pragma unroll
      for (int r = 0; r < 8; ++r){
        const float* hp = ws + O_HT + (long)(jl*8 + r)*Bn + bq*4;
        xs[r*4+0] = ldc(hp+0); xs[r*4+1] = ldc(hp+1);
        xs[r*4+2] = ldc(hp+2); xs[r*4+3] = ldc(hp+3);
      }
      float4 acc = make_float4(0,0,0,0);
      for (int k0 = 0; k0 < Hn; k0 += 8){
        const int src = k0 >> 3;
        float xv[32];
        #pragma unroll
        for (int q = 0; q < 32; ++q) xv[q] = __shfl(xs[q], src, 64);
        #pragma unroll
        for (int r = 0; r < 8; ++r){
          float w = wlds[((k0+r) << 6) + jl];
          acc.x += w*xv[r*4+0]; acc.y += w*xv[r*4+1];
          acc.z += w*xv[r*4+2]; acc.w += w*xv[r*4+3];
        }
      }
      const int j = blk*64 + jl;
      if (blk < 8){                      // hid
        float bias = w1b[j];
        stc(ws + O_HID + (long)(bq*4+0)*Hn + j, acc.x + bias);
        stc(ws + O_HID + (long)(bq*4+1)*Hn + j, acc.y + bias);
        stc(ws + O_HID + (long)(bq*4+2)*Hn + j, acc.z + bias);
        stc(ws + O_HID + (long)(bq*4+3)*Hn + j, acc.w + bias);
      } else if (blk < 28){              // gate (sigmoid)
        int f = j - J_GATE;
        float bias = gb[f];
        float* gp = ws + O_GT + (long)f*Bn + bq*4;
        stc(gp+0, sigm(acc.x+bias)); stc(gp+1, sigm(acc.y+bias));
        stc(gp+2, sigm(acc.z+bias)); stc(gp+3, sigm(acc.w+bias));
      } else if (blk < 60){              // xpart (permuted col layout)
        int j2 = j - J_XP;
        int pc = ((j2 & 511) << 2) | (j2 >> 9);
        float bias = bih[j2] + bhh[j2];
        float* xp = ws + O_XPT + (long)pc*Bn + bq*4;
        stc(xp+0, acc.x+bias); stc(xp+1, acc.y+bias);
        stc(xp+2, acc.z+bias); stc(xp+3, acc.w+bias);
      } else {                           // logits_{t-1} + argmax partials
        int v = j - J_LOG;
        float lv[4];
        if (v < Vn){
          float bias = outb[v];
          lv[0]=acc.x+bias; lv[1]=acc.y+bias; lv[2]=acc.z+bias; lv[3]=acc.w+bias;
          #pragma unroll
          for (int m = 0; m < 4; ++m)
            dout[((long)(bq*4+m)*Tn + (t-1))*Vn + v] = lv[m];
        } else {
          lv[0]=lv[1]=lv[2]=lv[3]=-1e30f;
        }
        int tile = blk - 60;
        #pragma unroll
        for (int m = 0; m < 4; ++m){
          float bv = lv[m]; int bi = v;
          #pragma unroll
          for (int off = 32; off; off >>= 1){
            float ov = __shfl_down(bv, off, 64);
            int   oi = __shfl_down(bi, off, 64);
            if (ov > bv || (ov == bv && oi < bi)){ bv = ov; bi = oi; }
          }
          if (jl == 0){
            int b = bq*4 + m;
            stc (ws + O_PMV + (long)b*NVT + tile, bv);
            stci((int*)(ws + O_PMI) + (long)b*NVT + tile, bi);
          }
        }
      }
    }
    gbar(cnt, 256u*(t+1));
    if (t == Tn) break;

    // ================= P2: per-b attention + argmax + emb + ctx (32 blocks) =========
    if (blk < 32){
      const int b = blk;
      float* hid_s = sbuf;             // 512
      float* va_s  = sbuf + 512;       // 512
      float* sval  = sbuf + 1024;      // 256
      float* wts_s = sbuf + 1280;      // 256
      float* mxp   = sbuf + 1536;      // [0]=max [1]=inv
      int*   rowp  = (int*)(sbuf + 1540);
      hid_s[tid] = ldc(ws + O_HID + (long)b*Hn + tid);
      va_s[tid]  = vaw[tid];
      if (t == 0){
        if (tid == 0) rowp[0] = 1;           // SOS
      } else if (tid < 64){
        float bv = -1e30f; int bi = 0x7fffffff;
        for (int q = tid; q < NVT; q += 64){
          float cv = ldc(ws + O_PMV + (long)b*NVT + q);
          if (cv > bv){ bv = cv; bi = ldci((const int*)(ws + O_PMI) + (long)b*NVT + q); }
        }
        #pragma unroll
        for (int off = 32; off; off >>= 1){
          float ov = __shfl_down(bv, off, 64);
          int   oi = __shfl_down(bi, off, 64);
          if (ov > bv || (ov == bv && oi < bi)){ bv = ov; bi = oi; }
        }
        if (tid == 0) rowp[0] = bi;
      }
      __syncthreads();
      // scores: thread-per-p (ENC normal loads, L2-warm)
      if (tid < Pn){
        const float* er = ws + O_ENC + ((long)b*Pn + tid)*Hn;
        float a0=0,a1=0,a2=0,a3=0;
        for (int k = 0; k < Hn; k += 16){
          float4 e0 = *(const float4*)(er + k);
          float4 e1 = *(const float4*)(er + k + 4);
          float4 e2 = *(const float4*)(er + k + 8);
          float4 e3 = *(const float4*)(er + k + 12);
          const float* hh = hid_s + k;
          const float* vv = va_s + k;
          a0 += fmaxf(hh[0]+e0.x,0.f)*vv[0] + fmaxf(hh[1]+e0.y,0.f)*vv[1]
              + fmaxf(hh[2]+e0.z,0.f)*vv[2] + fmaxf(hh[3]+e0.w,0.f)*vv[3];
          a1 += fmaxf(hh[4]+e1.x,0.f)*vv[4] + fmaxf(hh[5]+e1.y,0.f)*vv[5]
              + fmaxf(hh[6]+e1.z,0.f)*vv[6] + fmaxf(hh[7]+e1.w,0.f)*vv[7];
          a2 += fmaxf(hh[8]+e2.x,0.f)*vv[8] + fmaxf(hh[9]+e2.y,0.f)*vv[9]
              + fmaxf(hh[10]+e2.z,0.f)*vv[10] + fmaxf(hh[11]+e2.w,0.f)*vv[11];
          a3 += fmaxf(hh[12]+e3.x,0.f)*vv[12] + fmaxf(hh[13]+e3.y,0.f)*vv[13]
              + fmaxf(hh[14]+e3.z,0.f)*vv[14] + fmaxf(hh[15]+e3.w,0.f)*vv[15];
        }
        sval[tid] = (a0+a1)+(a2+a3) + vab[0];
      }
      __syncthreads();
      if (tid < 64){
        float m = -1e30f;
        for (int p = tid; p < Pn; p += 64) m = fmaxf(m, sval[p]);
        #pragma unroll
        for (int off = 32; off; off >>= 1) m = fmaxf(m, __shfl_xor(m, off, 64));
        float sm = 0.f;
        for (int p = tid; p < Pn; p += 64) sm += expf(sval[p] - m);
        #pragma unroll
        for (int off = 32; off; off >>= 1) sm += __shfl_xor(sm, off, 64);
        if (tid == 0){ mxp[0] = m; mxp[1] = 1.0f/sm; }
      }
      __syncthreads();
      if (tid < Pn){
        float wv = expf(sval[tid] - mxp[0]) * mxp[1];
        wts_s[tid] = wv;
        dout[(long)Bn*Tn*Vn + 2L*Bn*Hn + ((long)b*Tn + t)*Pn + tid] = wv;
      }
      __syncthreads();
      // emb half of x
      {
        int row = rowp[0];
        stc(ws + O_XT + (long)tid*Bn + b, emb[(long)row*En + tid]);
      }
      // ctx half of x (feat normal loads; gate coherent)
      for (int f = tid; f < Fn; f += 512){
        const float* fp = feat + (long)b*Pn*Fn + f;
        float a0=0,a1=0,a2=0,a3=0;
        for (int p = 0; p < Pn; p += 4){
          a0 += wts_s[p+0] * fp[(long)(p+0)*Fn];
          a1 += wts_s[p+1] * fp[(long)(p+1)*Fn];
          a2 += wts_s[p+2] * fp[(long)(p+2)*Fn];
          a3 += wts_s[p+3] * fp[(long)(p+3)*Fn];
        }
        float g = ldc(ws + O_GT + (long)f*Bn + b);
        stc(ws + O_XT + (long)(En + f)*Bn + b, ((a0+a1)+(a2+a3))*g);
      }
    }
    gbar(cnt + 32, 256u*(t+1));

    // ================= P3: Wih GEMM (LDS-chunked x) + LSTM update =================
    {
      const int c = tid & 7, ks = tid >> 3;      // 8 pc-cols x 64 k-slot pairs
      const int pc0 = blk*8;
      const float* wg = ws + O_WIHT + pc0 + c;
      float4 acc4[8];
      #pragma unroll
      for (int q = 0; q < 8; ++q) acc4[q] = make_float4(0,0,0,0);
      // prefetch chunk 0 into regs (coherent, coalesced)
      float xreg[8];
      #pragma unroll
      for (int r = 0; r < 8; ++r){
        int idx = r*512 + tid;
        xreg[r] = ldc(ws + O_XT + (long)(idx >> 5)*Bn + (idx & 31));
      }
      for (int ch = 0; ch < 14; ++ch){
        __syncthreads();                 // xbuf reusable
        #pragma unroll
        for (int r = 0; r < 8; ++r){
          int idx = r*512 + tid;
          sbuf[(idx >> 5)*36 + (idx & 31)] = xreg[r];
        }
        __syncthreads();
        if (ch < 13){
          int k0 = (ch+1)*128;
          #pragma unroll
          for (int r = 0; r < 8; ++r){
            int idx = r*512 + tid;
            xreg[r] = ldc(ws + O_XT + (long)(k0 + (idx >> 5))*Bn + (idx & 31));
          }
        }
        const int kg0 = ch*128;
        #pragma unroll
        for (int kk = 0; kk < 2; ++kk){
          int kl = ks*2 + kk;
          float w = wg[(long)(kg0 + kl)*G4];
          const float* xb = sbuf + kl*36;
          #pragma unroll
          for (int bq2 = 0; bq2 < 8; ++bq2){
            float4 x = *(const float4*)(xb + bq2*4);
            fma4(acc4[bq2], x, w);
          }
        }
      }
      // reduce over ks within wave (lane = (ks&7)*8 + c): offsets 8,16,32
      #pragma unroll
      for (int off = 8; off <= 32; off <<= 1){
        #pragma unroll
        for (int q = 0; q < 8; ++q){
          acc4[q].x += __shfl_xor(acc4[q].x, off, 64);
          acc4[q].y += __shfl_xor(acc4[q].y, off, 64);
          acc4[q].z += __shfl_xor(acc4[q].z, off, 64);
          acc4[q].w += __shfl_xor(acc4[q].w, off, 64);
        }
      }
      __syncthreads();                   // done reading xbuf; reuse as reduce buf
      const int wv = tid >> 6, lane = tid & 63;
      if (lane < 8){                     // lane == c, holds wave-sum for col c
        float* rb = sbuf + ((wv*8 + lane)*32);
        #pragma unroll
        for (int q = 0; q < 8; ++q) *(float4*)(rb + q*4) = acc4[q];
      }
      __syncthreads();
      if (tid < 256){
        int cc = tid >> 5, b = tid & 31;
        float s = 0.f;
        #pragma unroll
        for (int w2 = 0; w2 < 8; ++w2) s += sbuf[(w2*8 + cc)*32 + b];
        s += ldc(ws + O_XPT + (long)(pc0 + cc)*Bn + b);
        sbuf[2048 + cc*32 + b] = s;
      }
      __syncthreads();
      if (tid < 64){
        int il = tid >> 5, b = tid & 31;
        int i = blk*2 + il;
        float gi  = sbuf[2048 + (il*4+0)*32 + b];
        float gf  = sbuf[2048 + (il*4+1)*32 + b];
        float gg2 = sbuf[2048 + (il*4+2)*32 + b];
        float go  = sbuf[2048 + (il*4+3)*32 + b];
        float c_ = ws[O_C + (long)b*Hn + i];           // block-private
        float cn = sigm(gf)*c_ + sigm(gi)*tanhf(gg2);
        float hn = sigm(go)*tanhf(cn);
        ws[O_C + (long)b*Hn + i] = cn;                 // block-private
        stc(ws + O_HT + (long)i*Bn + b, hn);           // coherent
        if (t == Tn-1){
          dout[(long)Bn*Tn*Vn + (long)b*Hn + i] = hn;
          dout[(long)Bn*Tn*Vn + (long)Bn*Hn + (long)b*Hn + i] = cn;
        }
      }
    }
    gbar(cnt + 64, 256u*(t+1));
  }
}

} // anonymous namespace

extern "C" void kernel_launch(void* const* d_in, const int* in_sizes, int n_in,
                              void* d_out, int out_size, void* d_ws, size_t ws_size,
                              hipStream_t stream)
{
  (void)in_sizes; (void)n_in; (void)out_size; (void)ws_size;
  const float* feat = (const float*)d_in[0];
  const float* emb  = (const float*)d_in[3];
  const float* w1w  = (const float*)d_in[4];
  const float* w1b  = (const float*)d_in[5];
  const float* w2w  = (const float*)d_in[6];
  const float* w2b  = (const float*)d_in[7];
  const float* vaw  = (const float*)d_in[8];
  const float* vab  = (const float*)d_in[9];
  const float* wih  = (const float*)d_in[10];
  const float* whh  = (const float*)d_in[11];
  const float* bih  = (const float*)d_in[12];
  const float* bhh  = (const float*)d_in[13];
  const float* outw = (const float*)d_in[14];
  const float* outb = (const float*)d_in[15];
  const float* ihw  = (const float*)d_in[16];
  const float* ihb  = (const float*)d_in[17];
  const float* icw  = (const float*)d_in[18];
  const float* icb  = (const float*)d_in[19];
  const float* gw   = (const float*)d_in[20];
  const float* gb   = (const float*)d_in[21];
  float* ws  = (float*)d_ws;
  float* out = (float*)d_out;

  // reset barrier counters (async memset is graph-capturable)
  hipMemsetAsync((char*)d_ws + O_CNT*sizeof(float), 0, 512, stream);

  // setup: transposes of ihw/icw into ENC alias, mean, h0/c0
  k_tr_s<<<dim3(40,16),  256, 0, stream>>>(ihw,  ws + O_IHCT,       Hn, Fn, 1024);
  k_tr_s<<<dim3(40,16),  256, 0, stream>>>(icw,  ws + O_IHCT + 512, Hn, Fn, 1024);
  k_mean<<<160, 256, 0, stream>>>(feat, ws);
  k_h0c0<<<16, 512, 0, stream>>>(ihb, icb, ws);
  // persistent weight transposes
  k_tr_s<<<dim3(16,16),  256, 0, stream>>>(w1w,  ws + O_WCAT,          Hn, Hn, NCAT);
  k_tr_s<<<dim3(16,40),  256, 0, stream>>>(gw,   ws + O_WCAT + J_GATE, Fn, Hn, NCAT);
  k_tr_s<<<dim3(16,64),  256, 0, stream>>>(whh,  ws + O_WCAT + J_XP,   G4, Hn, NCAT);
  k_tr_s<<<dim3(16,313), 256, 0, stream>>>(outw, ws + O_WCAT + J_LOG,  Vn, Hn, NCAT);
  k_tr_wih<<<dim3(56,64), 256, 0, stream>>>(wih, ws);
  k_tr_s<<<dim3(40,16),  256, 0, stream>>>(w2w,  ws + O_W2T,           Hn, Fn, Hn);
  k_encproj<<<392, 512, 0, stream>>>(feat, w2b, ws);

  // the whole decode loop: one cooperative launch (co-residency guarantee)
  void* kargs[] = { (void*)&feat, (void*)&emb, (void*)&vaw, (void*)&vab,
                    (void*)&w1b, (void*)&gb, (void*)&bih, (void*)&bhh,
                    (void*)&outb, (void*)&ws, (void*)&out };
  hipLaunchCooperativeKernel((const void*)k_decode, dim3(NBLK), dim3(512),
                             kargs, 0, stream);
}

// Round 9
// 6517.141 us; speedup vs baseline: 2.6611x; 1.7453x over previous
//
#include <hip/hip_runtime.h>
#include <hip/hip_cooperative_groups.h>
#include <math.h>

#define RI __restrict__

namespace {

constexpr int Hn=512, En=512, Vn=10000, Fn=1280, Pn=196, Bn=32, Tn=80;
constexpr int G4 = 2048, KX = 1792;
constexpr int NCAT = 13888;          // 512 hid + 1280 gate + 2048 xp + 10048 logits(pad)
constexpr int NVT = 157;
constexpr int J_GATE = 512, J_XP = 1792, J_LOG = 3840;
constexpr int NBLK = 256;

// ---- workspace layout (float indices) ----
constexpr long O_ENC  = 0;                           // [B*P][H]  (static after setup)
constexpr long O_W2T  = O_ENC  + (long)Bn*Pn*Hn;     // [F][H]
constexpr long O_WCAT = O_W2T  + (long)Fn*Hn;        // [512][NCAT] (w1T|gwT|whhT|owT)
constexpr long O_WIHT = O_WCAT + (long)Hn*NCAT;      // [KX][2048] permuted cols (pc=i*4+g)
constexpr long O_H    = O_WIHT + (long)KX*G4;        // (unused in decode)
constexpr long O_HT   = O_H    + (long)Bn*Hn;        // [H][B]   coherent
constexpr long O_C    = O_HT   + (long)Hn*Bn;        // [B][H]   block-private (P3)
constexpr long O_HID  = O_C    + (long)Bn*Hn;        // [B][H]   coherent
constexpr long O_GT   = O_HID  + (long)Bn*Hn;        // [B][F]   coherent  (layout changed)
constexpr long O_XPT  = O_GT   + (long)Bn*Fn;        // [2048 pc][B] coherent
constexpr long O_XT   = O_XPT  + (long)G4*Bn;        // [B][KX]  coherent  (layout changed)
constexpr long O_PMV  = O_XT   + (long)Bn*KX;        // [B][157] coherent
constexpr long O_PMI  = O_PMV  + (long)Bn*NVT;       // [B][157] int coherent
constexpr long O_SVAL = O_PMI  + (long)Bn*NVT;       // [B][196] coherent
constexpr long O_SEL  = O_SVAL + (long)Bn*Pn;        // [B] int  coherent
constexpr long O_CNT  = O_SEL  + 64;                 // 4 barrier counters (128B apart)
// setup-only aliases inside O_ENC (consumed before k_encproj overwrites)
constexpr long O_IHCT  = O_ENC;                      // [1280][1024] (ihwT|icwT)
constexpr long O_MEANT = O_ENC + (long)Fn*1024;      // [F][B]

__device__ __forceinline__ float sigm(float x){ return 1.0f/(1.0f+expf(-x)); }
__device__ __forceinline__ void fma4(float4& a, const float4 x, const float w){
  a.x += w*x.x; a.y += w*x.y; a.z += w*x.z; a.w += w*x.w;
}
// coherent (agent-scope relaxed) accessors
__device__ __forceinline__ float ldc(const float* p){
  return __hip_atomic_load(p, __ATOMIC_RELAXED, __HIP_MEMORY_SCOPE_AGENT);
}
__device__ __forceinline__ void stc(float* p, float v){
  __hip_atomic_store(p, v, __ATOMIC_RELAXED, __HIP_MEMORY_SCOPE_AGENT);
}
__device__ __forceinline__ int ldci(const int* p){
  return __hip_atomic_load(p, __ATOMIC_RELAXED, __HIP_MEMORY_SCOPE_AGENT);
}
__device__ __forceinline__ void stci(int* p, int v){
  __hip_atomic_store(p, v, __ATOMIC_RELAXED, __HIP_MEMORY_SCOPE_AGENT);
}
__device__ __forceinline__ float2 ldc2(const float* p){
  union { unsigned long long u; float2 f; } c;
  c.u = __hip_atomic_load((const unsigned long long*)p,
                          __ATOMIC_RELAXED, __HIP_MEMORY_SCOPE_AGENT);
  return c.f;
}

// relaxed counter barrier: no acquire/release fence -> L2 stays warm.
__device__ __forceinline__ void gbar(unsigned* cnt, unsigned target){
  __syncthreads();
  if (threadIdx.x == 0){
    __hip_atomic_fetch_add(cnt, 1u, __ATOMIC_RELAXED, __HIP_MEMORY_SCOPE_AGENT);
    while (__hip_atomic_load(cnt, __ATOMIC_RELAXED, __HIP_MEMORY_SCOPE_AGENT) < target)
      __builtin_amdgcn_s_sleep(2);
  }
  __syncthreads();
}

// ---------- transpose with dst stride: dst[c*S + r] = src[r*C + c] ----------
__global__ __launch_bounds__(256) void k_tr_s(const float* RI src, float* RI dst,
                                              int R, int C, int S){
  __shared__ float t[32][33];
  int tc0 = blockIdx.x*32, tr0 = blockIdx.y*32;
  int lx = threadIdx.x & 31, ly = threadIdx.x >> 5;
  for (int i = ly; i < 32; i += 8){
    int r = tr0 + i, c = tc0 + lx;
    t[i][lx] = (r < R && c < C) ? src[(long)r*C + c] : 0.f;
  }
  __syncthreads();
  for (int i = ly; i < 32; i += 8){
    int c = tc0 + i, r = tr0 + lx;
    if (c < C && r < R) dst[(long)c*S + r] = t[lx][i];
  }
}

// ---------- wih transpose, gate-interleaved cols: WIHT[k][pc]=wih[j][k], pc=(j&511)*4+(j>>9)
__global__ __launch_bounds__(256) void k_tr_wih(const float* RI src, float* RI ws){
  __shared__ float t[32][33];
  int tk0 = blockIdx.x*32, tj0 = blockIdx.y*32;
  int lx = threadIdx.x & 31, ly = threadIdx.x >> 5;
  for (int i = ly; i < 32; i += 8){
    int j = tj0 + i, k = tk0 + lx;
    t[i][lx] = src[(long)j*KX + k];
  }
  __syncthreads();
  for (int i = ly; i < 32; i += 8){
    int k = tk0 + i, j = tj0 + lx;
    int pc = ((j & 511) << 2) | (j >> 9);
    ws[O_WIHT + (long)k*G4 + pc] = t[lx][i];
  }
}

// ---------- meanT[f][b] ----------
__global__ __launch_bounds__(256) void k_mean(const float* RI feat, float* RI ws){
  int blk = blockIdx.x;             // 160 = 32 b x 5 f-tiles
  int b = blk / 5, ft = blk % 5;
  int f = ft*256 + threadIdx.x;
  float s = 0.f;
  const float* fp = feat + (long)b*Pn*Fn + f;
  for (int p = 0; p < Pn; ++p) s += fp[(long)p*Fn];
  ws[O_MEANT + (long)f*Bn + b] = s * (1.0f/Pn);
}

// ---------- h0,c0 ----------
__global__ __launch_bounds__(512) void k_h0c0(const float* RI ihb, const float* RI icb,
                                              float* RI ws){
  int tid = threadIdx.x;
  int jl = tid & 63, bq = tid >> 6;
  int j = blockIdx.x*64 + jl;
  const float* wp = ws + O_IHCT + j;
  const float* xp = ws + O_MEANT + bq*4;
  float4 acc = make_float4(0,0,0,0);
  for (int k = 0; k < Fn; ++k){
    float w = wp[(long)k*1024];
    float4 x = *(const float4*)(xp + (long)k*Bn);
    fma4(acc, x, w);
  }
  float va[4] = {acc.x, acc.y, acc.z, acc.w};
  if (j < Hn){
    float bias = ihb[j];
    #pragma unroll
    for (int m = 0; m < 4; ++m){
      int b = bq*4 + m;
      ws[O_HT + (long)j*Bn + b] = va[m] + bias;
    }
  } else {
    int j2 = j - Hn;
    float bias = icb[j2];
    #pragma unroll
    for (int m = 0; m < 4; ++m)
      ws[O_C + (long)(bq*4+m)*Hn + j2] = va[m] + bias;
  }
}

// ---------- enc_proj: 392 blocks = 98 rt x 4 ct ----------
__global__ __launch_bounds__(512) void k_encproj(const float* RI feat, const float* RI w2b,
                                                 float* RI ws){
  __shared__ __align__(16) float xs[64*65];
  const int blk = blockIdx.x;
  const int rt = blk >> 2, ct = blk & 3;
  const int r0 = rt*64, j0 = ct*128;
  const int tid = threadIdx.x;
  const int jq = tid & 31, rg = tid >> 5;
  const int rw = tid >> 3, kc = (tid & 7)*8;
  const float* w2t = ws + O_W2T + j0 + jq*4;
  float4 a0 = make_float4(0,0,0,0), a1 = a0, a2 = a0, a3 = a0;
  for (int k0 = 0; k0 < Fn; k0 += 64){
    __syncthreads();
    {
      const float* fp = feat + (long)(r0+rw)*Fn + k0 + kc;
      float4 v0 = *(const float4*)(fp);
      float4 v1 = *(const float4*)(fp + 4);
      float* xr = xs + rw*65 + kc;
      xr[0]=v0.x; xr[1]=v0.y; xr[2]=v0.z; xr[3]=v0.w;
      xr[4]=v1.x; xr[5]=v1.y; xr[6]=v1.z; xr[7]=v1.w;
    }
    __syncthreads();
    #pragma unroll 4
    for (int kk = 0; kk < 64; ++kk){
      float4 w = *(const float4*)(w2t + (long)(k0+kk)*Hn);
      const float* xp = xs + (rg*4)*65 + kk;
      fma4(a0, w, xp[0]);
      fma4(a1, w, xp[65]);
      fma4(a2, w, xp[130]);
      fma4(a3, w, xp[195]);
    }
  }
  float4 b4 = *(const float4*)(w2b + j0 + jq*4);
  float4 out[4] = {a0,a1,a2,a3};
  #pragma unroll
  for (int m = 0; m < 4; ++m){
    long r = r0 + rg*4 + m;
    float4 o = out[m];
    o.x += b4.x; o.y += b4.y; o.z += b4.z; o.w += b4.w;
    *(float4*)(ws + O_ENC + r*Hn + j0 + jq*4) = o;
  }
}

// ---------- the whole 80-step decode: ONE cooperative kernel, relaxed barriers ----------
__global__ __launch_bounds__(512) void k_decode(
    const float* RI feat, const float* RI emb, const float* RI vaw, const float* RI vab,
    const float* RI w1b, const float* RI gb, const float* RI bih, const float* RI bhh,
    const float* RI outb, float* RI ws, float* RI dout)
{
  __shared__ __align__(16) float wlds[32768];    // 128 KB pinned WCAT slice [k][64 j]
  __shared__ __align__(16) float sbuf[4608];     // 18 KB phase scratch
  const int blk = blockIdx.x, tid = threadIdx.x;
  const int jl = tid & 63, bq = tid >> 6;
  unsigned* cnt = (unsigned*)(ws + O_CNT);

  if (blk < 217){
    const float* wg = ws + O_WCAT + blk*64;
    for (int idx = tid; idx < 512*64; idx += 512){
      int k = idx >> 6, j = idx & 63;
      wlds[idx] = wg[(long)k*NCAT + j];
    }
  }
  __syncthreads();

  for (int t = 0; t <= Tn; ++t){
    // ============== P1: unified h-GEMM (LDS weights, LDS-chunked HT) ==============
    bool p1act;
    if (t == Tn)      p1act = (blk >= 60 && blk < 217);
    else if (t == 0)  p1act = (blk < 60);
    else              p1act = (blk < 217);
    if (p1act){
      float4 acc = make_float4(0,0,0,0);
      float2 pre0 = ldc2(ws + O_HT + tid*2);
      float2 pre1 = ldc2(ws + O_HT + 1024 + tid*2);
      for (int c8 = 0; c8 < 8; ++c8){
        __syncthreads();
        *(float2*)(sbuf + tid*2) = pre0;
        *(float2*)(sbuf + 1024 + tid*2) = pre1;
        __syncthreads();
        if (c8 < 7){
          pre0 = ldc2(ws + O_HT + (long)(c8+1)*2048 + tid*2);
          pre1 = ldc2(ws + O_HT + (long)(c8+1)*2048 + 1024 + tid*2);
        }
        #pragma unroll 8
        for (int kk = 0; kk < 64; ++kk){
          float w = wlds[(long)(c8*64 + kk)*64 + jl];
          float4 x = *(const float4*)(sbuf + kk*32 + bq*4);
          fma4(acc, x, w);
        }
      }
      __syncthreads();                  // sbuf free for epilogue staging
      const int j = blk*64 + jl;
      if (blk < 8){                      // hid -> HID[b][H]
        float bias = w1b[j];
        stc(ws + O_HID + (long)(bq*4+0)*Hn + j, acc.x + bias);
        stc(ws + O_HID + (long)(bq*4+1)*Hn + j, acc.y + bias);
        stc(ws + O_HID + (long)(bq*4+2)*Hn + j, acc.z + bias);
        stc(ws + O_HID + (long)(bq*4+3)*Hn + j, acc.w + bias);
      } else if (blk < 28){              // gate -> GT[b][f]
        int f = j - J_GATE;
        float bias = gb[f];
        stc(ws + O_GT + (long)(bq*4+0)*Fn + f, sigm(acc.x + bias));
        stc(ws + O_GT + (long)(bq*4+1)*Fn + f, sigm(acc.y + bias));
        stc(ws + O_GT + (long)(bq*4+2)*Fn + f, sigm(acc.z + bias));
        stc(ws + O_GT + (long)(bq*4+3)*Fn + f, sigm(acc.w + bias));
      } else if (blk < 60){              // xpart -> XPT[pc][B] via LDS stage (full-line)
        int j2 = j - J_XP;
        float bias = bih[j2] + bhh[j2];
        sbuf[jl*33 + bq*4+0] = acc.x + bias;
        sbuf[jl*33 + bq*4+1] = acc.y + bias;
        sbuf[jl*33 + bq*4+2] = acc.z + bias;
        sbuf[jl*33 + bq*4+3] = acc.w + bias;
        __syncthreads();
        #pragma unroll
        for (int r = 0; r < 4; ++r){
          int idx = r*512 + tid;
          int row = idx >> 5, b = idx & 31;
          int j2r = (blk-28)*64 + row;
          int pc = ((j2r & 511) << 2) | (j2r >> 9);
          stc(ws + O_XPT + (long)pc*Bn + b, sbuf[row*33 + b]);
        }
      } else {                           // logits_{t-1} + argmax partials
        int v = j - J_LOG;
        float lv[4];
        if (v < Vn){
          float bias = outb[v];
          lv[0]=acc.x+bias; lv[1]=acc.y+bias; lv[2]=acc.z+bias; lv[3]=acc.w+bias;
          #pragma unroll
          for (int m = 0; m < 4; ++m)
            dout[((long)(bq*4+m)*Tn + (t-1))*Vn + v] = lv[m];
        } else {
          lv[0]=lv[1]=lv[2]=lv[3]=-1e30f;
        }
        int tile = blk - 60;
        #pragma unroll
        for (int m = 0; m < 4; ++m){
          float bv = lv[m]; int bi = v;
          #pragma unroll
          for (int off = 32; off; off >>= 1){
            float ov = __shfl_down(bv, off, 64);
            int   oi = __shfl_down(bi, off, 64);
            if (ov > bv || (ov == bv && oi < bi)){ bv = ov; bi = oi; }
          }
          if (jl == 0){
            int b = bq*4 + m;
            stc (ws + O_PMV + (long)b*NVT + tile, bv);
            stci((int*)(ws + O_PMI) + (long)b*NVT + tile, bi);
          }
        }
      }
    }
    gbar(cnt, 256u*(t+1));
    if (t == Tn) break;

    // ============== P2a: scores (224 blocks) + argmax finalize (32) ==============
    if (blk < 224){
      const int b = blk & 31, part = blk >> 5;      // part 0..6
      float* hid_s = sbuf;              // 512
      float* va_s  = sbuf + 512;        // 512
      float* sv    = sbuf + 1024;       // 28
      hid_s[tid] = ldc(ws + O_HID + (long)b*Hn + tid);
      va_s[tid]  = vaw[tid];
      __syncthreads();
      const int w = tid >> 6, l = tid & 63;
      const int p0 = part*28;
      const float* eb = ws + O_ENC + (long)b*Pn*Hn;
      for (int p = p0 + w; p < p0 + 28; p += 8){
        const float* er = eb + (long)p*Hn;
        float4 e0 = *(const float4*)(er + l*4);
        float4 e1 = *(const float4*)(er + 256 + l*4);
        float4 h0 = *(const float4*)(hid_s + l*4);
        float4 h1 = *(const float4*)(hid_s + 256 + l*4);
        float4 v0 = *(const float4*)(va_s + l*4);
        float4 v1 = *(const float4*)(va_s + 256 + l*4);
        float s = fmaxf(h0.x+e0.x,0.f)*v0.x + fmaxf(h0.y+e0.y,0.f)*v0.y
                + fmaxf(h0.z+e0.z,0.f)*v0.z + fmaxf(h0.w+e0.w,0.f)*v0.w
                + fmaxf(h1.x+e1.x,0.f)*v1.x + fmaxf(h1.y+e1.y,0.f)*v1.y
                + fmaxf(h1.z+e1.z,0.f)*v1.z + fmaxf(h1.w+e1.w,0.f)*v1.w;
        #pragma unroll
        for (int off = 32; off; off >>= 1) s += __shfl_down(s, off, 64);
        if (l == 0) sv[p - p0] = s + vab[0];
      }
      __syncthreads();
      if (tid < 28) stc(ws + O_SVAL + (long)b*Pn + p0 + tid, sv[tid]);
    } else {
      const int b = blk - 224;
      if (t == 0){
        if (tid == 0) stci((int*)(ws + O_SEL) + b, 1);       // SOS
      } else if (tid < 64){
        float bv = -1e30f; int bi = 0x7fffffff;
        for (int q = tid; q < NVT; q += 64){
          float cv = ldc(ws + O_PMV + (long)b*NVT + q);
          if (cv > bv){ bv = cv; bi = ldci((const int*)(ws + O_PMI) + (long)b*NVT + q); }
        }
        #pragma unroll
        for (int off = 32; off; off >>= 1){
          float ov = __shfl_down(bv, off, 64);
          int   oi = __shfl_down(bi, off, 64);
          if (ov > bv || (ov == bv && oi < bi)){ bv = ov; bi = oi; }
        }
        if (tid == 0) stci((int*)(ws + O_SEL) + b, bi);
      }
    }
    gbar(cnt + 32, 256u*(t+1));

    // ============== P2b: local softmax + ctx + emb -> XT[b][k] (256 blocks) ==============
    {
      const int b = blk & 31, fr = blk >> 5;        // fr 0..7, f0 = fr*160
      const int f0 = fr*160;
      float* svl = sbuf;            // 196
      float* wts = sbuf + 208;      // 196
      if (tid < Pn) svl[tid] = ldc(ws + O_SVAL + (long)b*Pn + tid);
      if (tid == 0) ((int*)sbuf)[450] = ldci((const int*)(ws + O_SEL) + b);
      __syncthreads();
      if (tid < 64){
        float m = -1e30f;
        for (int p = tid; p < Pn; p += 64) m = fmaxf(m, svl[p]);
        #pragma unroll
        for (int off = 32; off; off >>= 1) m = fmaxf(m, __shfl_xor(m, off, 64));
        float sm = 0.f;
        for (int p = tid; p < Pn; p += 64) sm += expf(svl[p] - m);
        #pragma unroll
        for (int off = 32; off; off >>= 1) sm += __shfl_xor(sm, off, 64);
        if (tid == 0){ sbuf[448] = m; sbuf[449] = 1.0f/sm; }
      }
      __syncthreads();
      if (tid < Pn){
        float wv = expf(svl[tid] - sbuf[448]) * sbuf[449];
        wts[tid] = wv;
        if (fr == 0)
          dout[(long)Bn*Tn*Vn + 2L*Bn*Hn + ((long)b*Tn + t)*Pn + tid] = wv;
      }
      __syncthreads();
      // ctx slice: 160 f x 3 p-groups
      const int pp = tid / 160, fl = tid - pp*160;
      float a = 0.f;
      if (tid < 480){
        const int p0 = pp*66, pn = (pp == 2) ? 64 : 66;
        const float* fp = feat + ((long)b*Pn + p0)*Fn + f0 + fl;
        const float* wl = wts + p0;
        float a0=0.f, a1=0.f, a2=0.f, a3=0.f;
        int p = 0;
        for (; p + 4 <= pn; p += 4){
          a0 += wl[p+0] * fp[(long)(p+0)*Fn];
          a1 += wl[p+1] * fp[(long)(p+1)*Fn];
          a2 += wl[p+2] * fp[(long)(p+2)*Fn];
          a3 += wl[p+3] * fp[(long)(p+3)*Fn];
        }
        for (; p < pn; ++p) a0 += wl[p] * fp[(long)p*Fn];
        a = (a0 + a1) + (a2 + a3);
        if (pp > 0) sbuf[512 + (pp-1)*160 + fl] = a;
      }
      __syncthreads();
      if (tid < 160){
        float tot = a + sbuf[512 + tid] + sbuf[672 + tid];
        int f = f0 + tid;
        tot *= ldc(ws + O_GT + (long)b*Fn + f);
        stc(ws + O_XT + (long)b*KX + En + f, tot);
      }
      if (fr == 0){
        int row = ((int*)sbuf)[450];
        stc(ws + O_XT + (long)b*KX + tid, emb[(long)row*En + tid]);
      }
    }
    gbar(cnt + 64, 256u*(t+1));

    // ============== P3: Wih GEMM (XT[b][k] -> LDS transpose) + LSTM ==============
    {
      const int c = tid & 7, ks = tid >> 3;      // 8 pc-cols x 64 k-slot pairs
      const int pc0 = blk*8;
      const float* wg = ws + O_WIHT + pc0 + c;
      float4 acc4[8];
      #pragma unroll
      for (int q = 0; q < 8; ++q) acc4[q] = make_float4(0,0,0,0);
      float2 pre[4];
      #pragma unroll
      for (int r = 0; r < 4; ++r){
        int flat = r*1024 + tid*2;
        pre[r] = ldc2(ws + O_XT + (long)(flat >> 7)*KX + (flat & 127));
      }
      for (int ch = 0; ch < 14; ++ch){
        __syncthreads();
        #pragma unroll
        for (int r = 0; r < 4; ++r){
          int flat = r*1024 + tid*2;
          int kl = flat & 127, b = flat >> 7;
          sbuf[kl*36 + b]     = pre[r].x;
          sbuf[(kl+1)*36 + b] = pre[r].y;
        }
        __syncthreads();
        if (ch < 13){
          long k0n = (long)(ch+1)*128;
          #pragma unroll
          for (int r = 0; r < 4; ++r){
            int flat = r*1024 + tid*2;
            pre[r] = ldc2(ws + O_XT + (long)(flat >> 7)*KX + k0n + (flat & 127));
          }
        }
        const long kg0 = (long)ch*128;
        #pragma unroll
        for (int kk = 0; kk < 2; ++kk){
          int kl = ks*2 + kk;
          float w = wg[(kg0 + kl)*G4];
          const float* xb = sbuf + kl*36;
          #pragma unroll
          for (int q = 0; q < 8; ++q){
            float4 x = *(const float4*)(xb + q*4);
            fma4(acc4[q], x, w);
          }
        }
      }
      #pragma unroll
      for (int off = 8; off <= 32; off <<= 1){
        #pragma unroll
        for (int q = 0; q < 8; ++q){
          acc4[q].x += __shfl_xor(acc4[q].x, off, 64);
          acc4[q].y += __shfl_xor(acc4[q].y, off, 64);
          acc4[q].z += __shfl_xor(acc4[q].z, off, 64);
          acc4[q].w += __shfl_xor(acc4[q].w, off, 64);
        }
      }
      __syncthreads();                   // staging dead; reuse sbuf
      const int wv = tid >> 6, lane = tid & 63;
      if (lane < 8){
        float* rb = sbuf + (wv*8 + lane)*32;
        #pragma unroll
        for (int q = 0; q < 8; ++q) *(float4*)(rb + q*4) = acc4[q];
      }
      __syncthreads();
      if (tid < 256){
        int cc = tid >> 5, b = tid & 31;
        float s = 0.f;
        #pragma unroll
        for (int w2 = 0; w2 < 8; ++w2) s += sbuf[(w2*8 + cc)*32 + b];
        s += ldc(ws + O_XPT + (long)(pc0 + cc)*Bn + b);
        sbuf[2048 + cc*32 + b] = s;
      }
      __syncthreads();
      if (tid < 64){
        int il = tid >> 5, b = tid & 31;
        int i = blk*2 + il;
        float gi  = sbuf[2048 + (il*4+0)*32 + b];
        float gf  = sbuf[2048 + (il*4+1)*32 + b];
        float gg2 = sbuf[2048 + (il*4+2)*32 + b];
        float go  = sbuf[2048 + (il*4+3)*32 + b];
        float c_ = ws[O_C + (long)b*Hn + i];           // block-private
        float cn = sigm(gf)*c_ + sigm(gi)*tanhf(gg2);
        float hn = sigm(go)*tanhf(cn);
        ws[O_C + (long)b*Hn + i] = cn;
        stc(ws + O_HT + (long)i*Bn + b, hn);
        if (t == Tn-1){
          dout[(long)Bn*Tn*Vn + (long)b*Hn + i] = hn;
          dout[(long)Bn*Tn*Vn + (long)Bn*Hn + (long)b*Hn + i] = cn;
        }
      }
    }
    gbar(cnt + 96, 256u*(t+1));
  }
}

} // anonymous namespace

extern "C" void kernel_launch(void* const* d_in, const int* in_sizes, int n_in,
                              void* d_out, int out_size, void* d_ws, size_t ws_size,
                              hipStream_t stream)
{
  (void)in_sizes; (void)n_in; (void)out_size; (void)ws_size;
  const float* feat = (const float*)d_in[0];
  const float* emb  = (const float*)d_in[3];
  const float* w1w  = (const float*)d_in[4];
  const float* w1b  = (const float*)d_in[5];
  const float* w2w  = (const float*)d_in[6];
  const float* w2b  = (const float*)d_in[7];
  const float* vaw  = (const float*)d_in[8];
  const float* vab  = (const float*)d_in[9];
  const float* wih  = (const float*)d_in[10];
  const float* whh  = (const float*)d_in[11];
  const float* bih  = (const float*)d_in[12];
  const float* bhh  = (const float*)d_in[13];
  const float* outw = (const float*)d_in[14];
  const float* outb = (const float*)d_in[15];
  const float* ihw  = (const float*)d_in[16];
  const float* ihb  = (const float*)d_in[17];
  const float* icw  = (const float*)d_in[18];
  const float* icb  = (const float*)d_in[19];
  const float* gw   = (const float*)d_in[20];
  const float* gb   = (const float*)d_in[21];
  float* ws  = (float*)d_ws;
  float* out = (float*)d_out;

  // reset barrier counters
  hipMemsetAsync((char*)d_ws + O_CNT*sizeof(float), 0, 512, stream);

  // setup: transposes of ihw/icw into ENC alias, mean, h0/c0
  k_tr_s<<<dim3(40,16),  256, 0, stream>>>(ihw,  ws + O_IHCT,       Hn, Fn, 1024);
  k_tr_s<<<dim3(40,16),  256, 0, stream>>>(icw,  ws + O_IHCT + 512, Hn, Fn, 1024);
  k_mean<<<160, 256, 0, stream>>>(feat, ws);
  k_h0c0<<<16, 512, 0, stream>>>(ihb, icb, ws);
  // persistent weight transposes
  k_tr_s<<<dim3(16,16),  256, 0, stream>>>(w1w,  ws + O_WCAT,          Hn, Hn, NCAT);
  k_tr_s<<<dim3(16,40),  256, 0, stream>>>(gw,   ws + O_WCAT + J_GATE, Fn, Hn, NCAT);
  k_tr_s<<<dim3(16,64),  256, 0, stream>>>(whh,  ws + O_WCAT + J_XP,   G4, Hn, NCAT);
  k_tr_s<<<dim3(16,313), 256, 0, stream>>>(outw, ws + O_WCAT + J_LOG,  Vn, Hn, NCAT);
  k_tr_wih<<<dim3(56,64), 256, 0, stream>>>(wih, ws);
  k_tr_s<<<dim3(40,16),  256, 0, stream>>>(w2w,  ws + O_W2T,           Hn, Fn, Hn);
  k_encproj<<<392, 512, 0, stream>>>(feat, w2b, ws);

  // the whole decode loop: one cooperative launch (co-residency guarantee)
  void* kargs[] = { (void*)&feat, (void*)&emb, (void*)&vaw, (void*)&vab,
                    (void*)&w1b, (void*)&gb, (void*)&bih, (void*)&bhh,
                    (void*)&outb, (void*)&ws, (void*)&out };
  hipLaunchCooperativeKernel((const void*)k_decode, dim3(NBLK), dim3(512),
                             kargs, 0, stream);
}